// Round 1
// baseline (65540.607 us; speedup 1.0000x reference)
//
#include <hip/hip_runtime.h>

#define D 512

__device__ __forceinline__ float waveSum(float v) {
#pragma unroll
    for (int m = 32; m > 0; m >>= 1) v += __shfl_xor(v, m, 64);
    return v;
}
__device__ __forceinline__ float waveMin(float v) {
#pragma unroll
    for (int m = 32; m > 0; m >>= 1) v = fminf(v, __shfl_xor(v, m, 64));
    return v;
}
__device__ __forceinline__ float waveMax(float v) {
#pragma unroll
    for (int m = 32; m > 0; m >>= 1) v = fmaxf(v, __shfl_xor(v, m, 64));
    return v;
}

// ---------------- Kernel 1: m = A^T A (per s). grid (64 tiles, 64 s), 256 thr ----
__global__ __launch_bounds__(256) void syrk_kernel(const float* __restrict__ sp,
                                                   float* __restrict__ M,
                                                   float* __restrict__ Tw) {
    const int s = blockIdx.y;
    const int I = blockIdx.x >> 3, J = blockIdx.x & 7;
    const int tx = threadIdx.x & 15, ty = threadIdx.x >> 4;
    const float* __restrict__ A = sp + (size_t)s * D * D;
    __shared__ __align__(16) float As[64 * 68];
    __shared__ __align__(16) float Bs[64 * 68];
    float acc[4][4];
#pragma unroll
    for (int r = 0; r < 4; r++)
#pragma unroll
        for (int q = 0; q < 4; q++) acc[r][q] = 0.f;

    for (int k0 = 0; k0 < D; k0 += 64) {
        for (int e = threadIdx.x; e < 4096; e += 256) {
            const int col = e & 63, kr = e >> 6;
            As[kr * 68 + col] = A[(size_t)(k0 + kr) * D + I * 64 + col];
            Bs[kr * 68 + col] = A[(size_t)(k0 + kr) * D + J * 64 + col];
        }
        __syncthreads();
#pragma unroll 4
        for (int k = 0; k < 64; k++) {
            const float4 a = *(const float4*)&As[k * 68 + 4 * ty];
            const float4 b = *(const float4*)&Bs[k * 68 + 4 * tx];
            const float av[4] = {a.x, a.y, a.z, a.w};
            const float bv[4] = {b.x, b.y, b.z, b.w};
#pragma unroll
            for (int r = 0; r < 4; r++)
#pragma unroll
                for (int q = 0; q < 4; q++) acc[r][q] += av[r] * bv[q];
        }
        __syncthreads();
    }
#pragma unroll
    for (int r = 0; r < 4; r++) {
        float4 v4;
        v4.x = acc[r][0]; v4.y = acc[r][1]; v4.z = acc[r][2]; v4.w = acc[r][3];
        const size_t off = (size_t)s * D * D + (size_t)(I * 64 + 4 * ty + r) * D + J * 64 + 4 * tx;
        *(float4*)(M + off) = v4;
        *(float4*)(Tw + off) = v4;
    }
}

// ---------------- Kernel 2: Householder tridiagonalization. grid 64, 512 thr ----
__global__ __launch_bounds__(512) void tridiag_kernel(float* __restrict__ T,
                                                      float* __restrict__ dvec,
                                                      float* __restrict__ evec) {
    const int s = blockIdx.x;
    float* __restrict__ Ts = T + (size_t)s * D * D;
    const int tid = threadIdx.x, lane = tid & 63, wid = tid >> 6;
    __shared__ float v[D], p[D], w[D];
    __shared__ float red[8];
    __shared__ float sh_beta, sh_coef;
    __shared__ int sh_skip;

    for (int k = 0; k < D - 2; k++) {
        const int base = k + 1, n = D - 1 - k;
        // pass 1: row k trailing (== column below diag by symmetry) -> v, sumsq(a[1:])
        float part = 0.f;
        for (int i = tid; i < n; i += 512) {
            const float val = Ts[(size_t)k * D + base + i];
            v[i] = val;
            if (i > 0) part += val * val;
        }
        part = waveSum(part);
        if (lane == 0) red[wid] = part;
        __syncthreads();
        if (tid == 0) {
            float xn2 = 0.f;
            for (int q = 0; q < 8; q++) xn2 += red[q];
            const float a0 = v[0];
            dvec[s * D + k] = Ts[(size_t)k * D + k];
            if (xn2 <= 0.f) {
                evec[s * D + k] = a0;
                sh_skip = 1;
            } else {
                const float anorm = sqrtf(a0 * a0 + xn2);
                const float alpha = (a0 >= 0.f) ? -anorm : anorm;
                const float v0 = a0 - alpha;
                sh_beta = 2.f / (v0 * v0 + xn2);
                v[0] = v0;
                evec[s * D + k] = alpha;
                sh_skip = 0;
            }
        }
        __syncthreads();
        if (sh_skip) continue;
        const float beta = sh_beta;
        // symv: p = beta * A_trail * v  (wave per row, lanes over cols)
        for (int i = wid; i < n; i += 8) {
            const float* __restrict__ row = Ts + (size_t)(base + i) * D + base;
            float sum = 0.f;
            for (int j = lane; j < n; j += 64) sum += row[j] * v[j];
            sum = waveSum(sum);
            if (lane == 0) p[i] = beta * sum;
        }
        __syncthreads();
        // pv reduction
        float pp = 0.f;
        for (int i = tid; i < n; i += 512) pp += p[i] * v[i];
        pp = waveSum(pp);
        if (lane == 0) red[wid] = pp;
        __syncthreads();
        if (tid == 0) {
            float pv = 0.f;
            for (int q = 0; q < 8; q++) pv += red[q];
            sh_coef = 0.5f * beta * pv;
        }
        __syncthreads();
        const float coef = sh_coef;
        for (int i = tid; i < n; i += 512) w[i] = p[i] - coef * v[i];
        __syncthreads();
        // rank-2 update: A -= v w^T + w v^T (full trailing square kept symmetric)
        for (int i = wid; i < n; i += 8) {
            const float vi = v[i], wi = w[i];
            float* __restrict__ row = Ts + (size_t)(base + i) * D + base;
            for (int j = lane; j < n; j += 64) row[j] -= vi * w[j] + wi * v[j];
        }
        __syncthreads();
    }
    if (threadIdx.x == 0) {
        dvec[s * D + D - 2] = Ts[(size_t)(D - 2) * D + D - 2];
        evec[s * D + D - 2] = Ts[(size_t)(D - 2) * D + D - 1];
        dvec[s * D + D - 1] = Ts[(size_t)(D - 1) * D + D - 1];
        evec[s * D + D - 1] = 0.f;
    }
}

// ---------------- Kernel 3: bisection eigenvalues (ascending). grid 64, 512 thr --
__global__ __launch_bounds__(512) void bisect_kernel(const float* __restrict__ dvec,
                                                     const float* __restrict__ evec,
                                                     float* __restrict__ lam) {
    const int s = blockIdx.x, tid = threadIdx.x;
    const int lane = tid & 63, wid = tid >> 6;
    __shared__ float d[D], e2[D], ea[D];
    __shared__ float red[8];
    __shared__ float sh_lo, sh_hi;
    {
        const float dv = dvec[s * D + tid];
        const float ev = evec[s * D + tid];
        d[tid] = dv; ea[tid] = fabsf(ev); e2[tid] = ev * ev;
    }
    __syncthreads();
    const float rad = ea[tid] + ((tid > 0) ? ea[tid - 1] : 0.f);
    float lo = waveMin(d[tid] - rad);
    float hi = waveMax(d[tid] + rad);
    if (lane == 0) red[wid] = lo;
    __syncthreads();
    if (tid == 0) {
        float t = red[0];
        for (int q = 1; q < 8; q++) t = fminf(t, red[q]);
        sh_lo = t - 1e-3f * fmaxf(fabsf(t), 1.f);
    }
    __syncthreads();
    if (lane == 0) red[wid] = hi;
    __syncthreads();
    if (tid == 0) {
        float t = red[0];
        for (int q = 1; q < 8; q++) t = fmaxf(t, red[q]);
        sh_hi = t + 1e-3f * fmaxf(fabsf(t), 1.f);
    }
    __syncthreads();
    float a = sh_lo, b = sh_hi;
    const int j1 = tid + 1;
    for (int it = 0; it < 36; it++) {
        const float mid = 0.5f * (a + b);
        int cnt = 0;
        float q = d[0] - mid;
        cnt += (q < 0.f);
        for (int i = 1; i < D; i++) {
            float den = q;
            const float ad = fabsf(den);
            den = (ad < 1e-26f) ? ((den < 0.f) ? -1e-26f : 1e-26f) : den;
            q = d[i] - mid - e2[i - 1] / den;
            cnt += (q < 0.f);
        }
        if (cnt >= j1) b = mid; else a = mid;
    }
    lam[s * D + tid] = 0.5f * (a + b);
}

// ---------------- Kernel 4: sigma = m + 0.01*diag(lam); Cholesky; logdet --------
__global__ __launch_bounds__(512) void chol_kernel(float* __restrict__ M,
                                                   const float* __restrict__ lam,
                                                   float* __restrict__ logdet) {
    const int s = blockIdx.x, tid = threadIdx.x, lane = tid & 63, wid = tid >> 6;
    float* __restrict__ Ms = M + (size_t)s * D * D;
    __shared__ float col[D];
    __shared__ float sh_inv;
    Ms[(size_t)tid * D + tid] += 0.01f * lam[s * D + tid];
    __syncthreads();
    float logacc = 0.f;
    for (int j = 0; j < D; j++) {
        if (tid == 0) {
            const float pj = Ms[(size_t)j * D + j];
            const float l = sqrtf(pj);
            Ms[(size_t)j * D + j] = l;
            sh_inv = 1.f / l;
            logacc += logf(l);
        }
        __syncthreads();
        const float inv = sh_inv;
        for (int i = j + 1 + tid; i < D; i += 512) {
            const float val = Ms[(size_t)i * D + j] * inv;
            Ms[(size_t)i * D + j] = val;
            col[i] = val;
        }
        __syncthreads();
        for (int i = j + 1 + wid; i < D; i += 8) {
            const float li = col[i];
            float* __restrict__ row = Ms + (size_t)i * D;
            for (int kk = j + 1 + lane; kk <= i; kk += 64) row[kk] -= li * col[kk];
        }
        __syncthreads();
    }
    if (tid == 0) logdet[s] = 2.f * logacc;
}

// ---------------- Kernel 5: invert 64x64 diagonal blocks of L (transposed) ------
__global__ __launch_bounds__(64) void invdiag_kernel(const float* __restrict__ M,
                                                     float* __restrict__ invDT) {
    const int b = blockIdx.x, s = b >> 3, I = b & 7;
    const int c = threadIdx.x;
    __shared__ float Lsh[64 * 65];
    __shared__ float xsh[64 * 65];
    const float* __restrict__ Ms = M + (size_t)s * D * D;
    for (int e = c; e < 4096; e += 64) {
        const int i = e >> 6, k = e & 63;
        Lsh[i * 65 + k] = Ms[(size_t)(I * 64 + i) * D + I * 64 + k];
    }
    for (int i = 0; i < 64; i++) xsh[c * 65 + i] = (i == c) ? 1.f : 0.f;
    __syncthreads();
    for (int i = 0; i < 64; i++) {
        float t = xsh[c * 65 + i];
        for (int k = 0; k < i; k++) t -= Lsh[i * 65 + k] * xsh[c * 65 + k];
        xsh[c * 65 + i] = t / Lsh[i * 65 + i];
    }
    float* __restrict__ outp = invDT + (size_t)b * 4096 + c * 64;
    for (int i = 0; i < 64; i++) outp[i] = xsh[c * 65 + i];  // invDT[b][c][i] = invL[i][c]
}

// ---------------- Kernel 6: blocked trsm (z-panel in LDS) + maha + epilogue -----
// grid (32 n-panels, 64 s), 256 thr, dynamic LDS = (512*64 + 64*68)*4 = 145 KB
__global__ __launch_bounds__(256) void trsm_kernel(const float* __restrict__ M,
                                                   const float* __restrict__ invDT,
                                                   const float* __restrict__ x,
                                                   const float* __restrict__ mu,
                                                   const float* __restrict__ logdet,
                                                   float* __restrict__ out) {
    extern __shared__ float smem[];
    float* __restrict__ Z = smem;            // 512 x 64
    float* __restrict__ U = smem + D * 64;   // 64 x 68 (L-tile transposed / B scratch)
    const int s = blockIdx.y;
    const int n0 = blockIdx.x * 64;
    const int tid = threadIdx.x;
    const int tx = tid & 15, ty = tid >> 4;
    const float* __restrict__ Ms = M + (size_t)s * D * D;
    const float* __restrict__ mus = mu + s * D;

    for (int I = 0; I < 8; I++) {
        float acc[4][4];
#pragma unroll
        for (int r = 0; r < 4; r++) {
            const int irow = I * 64 + 4 * ty + r;
            const float m0 = mus[irow];
#pragma unroll
            for (int q = 0; q < 4; q++)
                acc[r][q] = x[(size_t)(n0 + 4 * tx + q) * D + irow] - m0;
        }
        for (int J = 0; J < I; J++) {
            __syncthreads();
            for (int e = tid; e < 4096; e += 256) {
                const int k = e & 63, i = e >> 6;
                U[k * 68 + i] = Ms[(size_t)(I * 64 + i) * D + J * 64 + k];
            }
            __syncthreads();
#pragma unroll 4
            for (int k = 0; k < 64; k++) {
                const float4 a = *(const float4*)&U[k * 68 + 4 * ty];
                const float4 b = *(const float4*)&Z[(J * 64 + k) * 64 + 4 * tx];
                const float av[4] = {a.x, a.y, a.z, a.w};
                const float bv[4] = {b.x, b.y, b.z, b.w};
#pragma unroll
                for (int r = 0; r < 4; r++)
#pragma unroll
                    for (int q = 0; q < 4; q++) acc[r][q] -= av[r] * bv[q];
            }
        }
        __syncthreads();
#pragma unroll
        for (int r = 0; r < 4; r++) {
            float4 v4;
            v4.x = acc[r][0]; v4.y = acc[r][1]; v4.z = acc[r][2]; v4.w = acc[r][3];
            *(float4*)&U[(4 * ty + r) * 68 + 4 * tx] = v4;
        }
        __syncthreads();
        {
            float zacc[4][4];
#pragma unroll
            for (int r = 0; r < 4; r++)
#pragma unroll
                for (int q = 0; q < 4; q++) zacc[r][q] = 0.f;
            const float* __restrict__ iD = invDT + (size_t)(s * 8 + I) * 4096;
#pragma unroll 4
            for (int k = 0; k < 64; k++) {
                const float4 a = *(const float4*)&iD[k * 64 + 4 * ty];
                const float4 b = *(const float4*)&U[k * 68 + 4 * tx];
                const float av[4] = {a.x, a.y, a.z, a.w};
                const float bv[4] = {b.x, b.y, b.z, b.w};
#pragma unroll
                for (int r = 0; r < 4; r++)
#pragma unroll
                    for (int q = 0; q < 4; q++) zacc[r][q] += av[r] * bv[q];
            }
#pragma unroll
            for (int r = 0; r < 4; r++) {
                float4 v4;
                v4.x = zacc[r][0]; v4.y = zacc[r][1]; v4.z = zacc[r][2]; v4.w = zacc[r][3];
                *(float4*)&Z[(I * 64 + 4 * ty + r) * 64 + 4 * tx] = v4;
            }
        }
    }
    __syncthreads();
    {
        const int c = tid & 63, part = tid >> 6;  // 4 parts x 128 rows
        float sum = 0.f;
        for (int i = part * 128; i < part * 128 + 128; i++) {
            const float z = Z[i * 64 + c];
            sum += z * z;
        }
        U[part * 64 + c] = sum;
    }
    __syncthreads();
    if (tid < 64) {
        const float mah = U[tid] + U[64 + tid] + U[128 + tid] + U[192 + tid];
        out[(size_t)(n0 + tid) * 64 + s] = -0.5f * (mah + logdet[s] + 940.993058f);
    }
}

extern "C" void kernel_launch(void* const* d_in, const int* in_sizes, int n_in,
                              void* d_out, int out_size, void* d_ws, size_t ws_size,
                              hipStream_t stream) {
    const float* x  = (const float*)d_in[0];   // (2048, 512)
    const float* mu = (const float*)d_in[1];   // (64, 1, 512)
    // d_in[2] = omega (softmax result unused by reference)
    const float* sp = (const float*)d_in[3];   // (64, 1, 512, 512)
    float* out = (float*)d_out;                // (2048, 64) fp32

    float* wsf  = (float*)d_ws;
    float* Mw   = wsf;                              // 64*512*512
    float* Tw   = wsf + (size_t)16777216;           // 64*512*512 (tridiag scratch)
    float* dvec = wsf + (size_t)33554432;           // 64*512
    float* evec = dvec + 32768;                     // 64*512
    float* lamv = evec + 32768;                     // 64*512
    float* logd = lamv + 32768;                     // 64
    float* invDT = Tw;                              // reuse: Tw dead after bisect

    syrk_kernel<<<dim3(64, 64), dim3(256), 0, stream>>>(sp, Mw, Tw);
    tridiag_kernel<<<dim3(64), dim3(512), 0, stream>>>(Tw, dvec, evec);
    bisect_kernel<<<dim3(64), dim3(512), 0, stream>>>(dvec, evec, lamv);
    chol_kernel<<<dim3(64), dim3(512), 0, stream>>>(Mw, lamv, logd);
    invdiag_kernel<<<dim3(512), dim3(64), 0, stream>>>(Mw, invDT);
    const size_t lds = (size_t)(D * 64 + 64 * 68) * sizeof(float);
    trsm_kernel<<<dim3(32, 64), dim3(256), lds, stream>>>(Mw, invDT, x, mu, logd, out);
}

// Round 2
// 23772.377 us; speedup vs baseline: 2.7570x; 2.7570x over previous
//
#include <hip/hip_runtime.h>

#define D 512
#define TWAVES 16

__device__ __forceinline__ float waveSum(float v) {
#pragma unroll
    for (int m = 32; m > 0; m >>= 1) v += __shfl_xor(v, m, 64);
    return v;
}
__device__ __forceinline__ float waveMin(float v) {
#pragma unroll
    for (int m = 32; m > 0; m >>= 1) v = fminf(v, __shfl_xor(v, m, 64));
    return v;
}
__device__ __forceinline__ float waveMax(float v) {
#pragma unroll
    for (int m = 32; m > 0; m >>= 1) v = fmaxf(v, __shfl_xor(v, m, 64));
    return v;
}

// ---------------- Kernel 1: m = A^T A (per s). grid (64 tiles, 64 s), 256 thr ----
__global__ __launch_bounds__(256) void syrk_kernel(const float* __restrict__ sp,
                                                   float* __restrict__ M,
                                                   float* __restrict__ Tw) {
    const int s = blockIdx.y;
    const int I = blockIdx.x >> 3, J = blockIdx.x & 7;
    const int tx = threadIdx.x & 15, ty = threadIdx.x >> 4;
    const float* __restrict__ A = sp + (size_t)s * D * D;
    __shared__ __align__(16) float As[64 * 68];
    __shared__ __align__(16) float Bs[64 * 68];
    float acc[4][4];
#pragma unroll
    for (int r = 0; r < 4; r++)
#pragma unroll
        for (int q = 0; q < 4; q++) acc[r][q] = 0.f;

    for (int k0 = 0; k0 < D; k0 += 64) {
        for (int e = threadIdx.x; e < 4096; e += 256) {
            const int col = e & 63, kr = e >> 6;
            As[kr * 68 + col] = A[(size_t)(k0 + kr) * D + I * 64 + col];
            Bs[kr * 68 + col] = A[(size_t)(k0 + kr) * D + J * 64 + col];
        }
        __syncthreads();
#pragma unroll 4
        for (int k = 0; k < 64; k++) {
            const float4 a = *(const float4*)&As[k * 68 + 4 * ty];
            const float4 b = *(const float4*)&Bs[k * 68 + 4 * tx];
            const float av[4] = {a.x, a.y, a.z, a.w};
            const float bv[4] = {b.x, b.y, b.z, b.w};
#pragma unroll
            for (int r = 0; r < 4; r++)
#pragma unroll
                for (int q = 0; q < 4; q++) acc[r][q] += av[r] * bv[q];
        }
        __syncthreads();
    }
#pragma unroll
    for (int r = 0; r < 4; r++) {
        float4 v4;
        v4.x = acc[r][0]; v4.y = acc[r][1]; v4.z = acc[r][2]; v4.w = acc[r][3];
        const size_t off = (size_t)s * D * D + (size_t)(I * 64 + 4 * ty + r) * D + J * 64 + 4 * tx;
        *(float4*)(M + off) = v4;
        *(float4*)(Tw + off) = v4;
    }
}

// ---------------- Kernel 2: Householder tridiagonalization (2-pass, fused) ------
// One WG (1024 thr / 16 waves) per matrix. Full-square symmetric storage.
// Per step: A) norm+finalize from LDS buffer (2 bars)  B) symv+pv (2 bars)
//           C) rank-2 update + extract next pivot row into alternate buffer (1 bar)
__global__ __launch_bounds__(1024) void tridiag_kernel(float* __restrict__ T,
                                                       float* __restrict__ dvec,
                                                       float* __restrict__ evec) {
    const int s = blockIdx.x;
    float* __restrict__ Ts = T + (size_t)s * D * D;
    const int tid = threadIdx.x, lane = tid & 63, wid = tid >> 6;
    __shared__ __align__(16) float bufA[D];
    __shared__ __align__(16) float bufB[D];
    __shared__ __align__(16) float pf[D];
    __shared__ float red[TWAVES];
    __shared__ float sh_beta, sh_twoc;
    __shared__ int sh_skip;

    // seed: row 0 into bufA
    for (int j = tid; j < D; j += 1024) bufA[j] = Ts[j];
    __syncthreads();

    for (int k = 0; k < D - 2; k++) {
        float* __restrict__ vb = (k & 1) ? bufB : bufA;
        float* __restrict__ nb = (k & 1) ? bufA : bufB;
        const int base = k + 1;
        const int j0 = base & ~63;

        // ---- stage A: xn2 = sum_{j>base} vb[j]^2 ----
        float part = 0.f;
        for (int j = base + 1 + tid; j < D; j += 1024) part += vb[j] * vb[j];
        part = waveSum(part);
        if (lane == 0) red[wid] = part;
        __syncthreads();
        if (tid == 0) {
            float xn2 = 0.f;
            for (int q = 0; q < TWAVES; q++) xn2 += red[q];
            const float a0 = vb[base];
            dvec[s * D + k] = vb[k];
            if (xn2 <= 0.f) {
                evec[s * D + k] = a0;
                sh_skip = 1;
            } else {
                const float anorm = sqrtf(a0 * a0 + xn2);
                const float alpha = (a0 >= 0.f) ? -anorm : anorm;
                const float v0 = a0 - alpha;
                sh_beta = 2.f / (v0 * v0 + xn2);
                vb[base] = v0;
                evec[s * D + k] = alpha;
                sh_skip = 0;
            }
            vb[k] = 0.f;             // zero-pad window below 'base'
            if (k >= 1) vb[k - 1] = 0.f;
        }
        __syncthreads();
        if (sh_skip) {
            for (int j = base + tid; j < D; j += 1024) nb[j] = Ts[(size_t)base * D + j];
            __syncthreads();
            continue;
        }
        const float beta = sh_beta;

        // ---- stage B: p = beta*A*v over rows i>=base; accumulate pv per wave ----
        float pvw = 0.f;
        for (int i = base + wid; i < D; i += TWAVES) {
            const float* __restrict__ row = Ts + (size_t)i * D;
            float ssum = 0.f;
            for (int j = j0 + 4 * lane; j < D; j += 256) {
                const float4 a = *(const float4*)&row[j];
                const float4 b = *(const float4*)&vb[j];
                ssum += a.x * b.x + a.y * b.y + a.z * b.z + a.w * b.w;
            }
            ssum = waveSum(ssum);
            if (lane == 0) {
                const float pi = beta * ssum;
                pf[i] = pi;
                pvw += pi * vb[i];
            }
        }
        if (lane == 0) red[wid] = pvw;
        __syncthreads();
        if (tid == 0) {
            float pv = 0.f;
            for (int q = 0; q < TWAVES; q++) pv += red[q];
            sh_twoc = beta * pv;     // = 2*coef
        }
        __syncthreads();
        const float twoc = sh_twoc;

        // ---- stage C: A[i][j] -= v_i*p_j + q_i*v_j, extract row 'base' -> nb ----
        for (int i = base + wid; i < D; i += TWAVES) {
            float* __restrict__ row = Ts + (size_t)i * D;
            const float vi = vb[i];
            const float qi = pf[i] - twoc * vi;
            const bool ex = (i == base);
            for (int j = j0 + 4 * lane; j < D; j += 256) {
                float4 a = *(float4*)&row[j];
                const float4 p4 = *(const float4*)&pf[j];
                const float4 v4 = *(const float4*)&vb[j];
                a.x -= vi * p4.x + qi * v4.x;
                a.y -= vi * p4.y + qi * v4.y;
                a.z -= vi * p4.z + qi * v4.z;
                a.w -= vi * p4.w + qi * v4.w;
                *(float4*)&row[j] = a;
                if (ex) {
                    if (j     >= base) nb[j]     = a.x;
                    if (j + 1 >= base) nb[j + 1] = a.y;
                    if (j + 2 >= base) nb[j + 2] = a.z;
                    if (j + 3 >= base) nb[j + 3] = a.w;
                }
            }
        }
        __syncthreads();
    }
    if (threadIdx.x == 0) {
        dvec[s * D + D - 2] = Ts[(size_t)(D - 2) * D + D - 2];
        evec[s * D + D - 2] = Ts[(size_t)(D - 2) * D + D - 1];
        dvec[s * D + D - 1] = Ts[(size_t)(D - 1) * D + D - 1];
        evec[s * D + D - 1] = 0.f;
    }
}

// ---------------- Kernel 3: bisection eigenvalues (ascending). grid 64, 512 thr --
__global__ __launch_bounds__(512) void bisect_kernel(const float* __restrict__ dvec,
                                                     const float* __restrict__ evec,
                                                     float* __restrict__ lam) {
    const int s = blockIdx.x, tid = threadIdx.x;
    const int lane = tid & 63, wid = tid >> 6;
    __shared__ float d[D], e2[D], ea[D];
    __shared__ float red[8];
    __shared__ float sh_lo, sh_hi;
    {
        const float dv = dvec[s * D + tid];
        const float ev = evec[s * D + tid];
        d[tid] = dv; ea[tid] = fabsf(ev); e2[tid] = ev * ev;
    }
    __syncthreads();
    const float rad = ea[tid] + ((tid > 0) ? ea[tid - 1] : 0.f);
    float lo = waveMin(d[tid] - rad);
    float hi = waveMax(d[tid] + rad);
    if (lane == 0) red[wid] = lo;
    __syncthreads();
    if (tid == 0) {
        float t = red[0];
        for (int q = 1; q < 8; q++) t = fminf(t, red[q]);
        sh_lo = t - 1e-3f * fmaxf(fabsf(t), 1.f);
    }
    __syncthreads();
    if (lane == 0) red[wid] = hi;
    __syncthreads();
    if (tid == 0) {
        float t = red[0];
        for (int q = 1; q < 8; q++) t = fmaxf(t, red[q]);
        sh_hi = t + 1e-3f * fmaxf(fabsf(t), 1.f);
    }
    __syncthreads();
    float a = sh_lo, b = sh_hi;
    const int j1 = tid + 1;
    for (int it = 0; it < 36; it++) {
        const float mid = 0.5f * (a + b);
        int cnt = 0;
        float q = d[0] - mid;
        cnt += (q < 0.f);
        for (int i = 1; i < D; i++) {
            float den = q;
            const float ad = fabsf(den);
            den = (ad < 1e-26f) ? ((den < 0.f) ? -1e-26f : 1e-26f) : den;
            q = d[i] - mid - e2[i - 1] / den;
            cnt += (q < 0.f);
        }
        if (cnt >= j1) b = mid; else a = mid;
    }
    lam[s * D + tid] = 0.5f * (a + b);
}

// ---------------- Kernel 4: Cholesky (upper-storage active, L stored transposed) --
// Active A kept in UPPER triangle (rows==cols by symmetry, coalesced). At step j,
// column j lives in LDS (extracted during previous rank-1 update). L is written
// TRANSPOSED: M[j*D+i] = L[i][j] (i>=j), filling rows the active region vacates.
__global__ __launch_bounds__(512) void chol_kernel(float* __restrict__ M,
                                                   const float* __restrict__ lam,
                                                   float* __restrict__ logdet) {
    const int s = blockIdx.x, tid = threadIdx.x, lane = tid & 63, wid = tid >> 6;
    float* __restrict__ Ms = M + (size_t)s * D * D;
    __shared__ __align__(16) float cbA[D];
    __shared__ __align__(16) float cbB[D];
    __shared__ float sh_inv, sh_l;
    Ms[(size_t)tid * D + tid] += 0.01f * lam[s * D + tid];
    __syncthreads();
    for (int j = tid; j < D; j += 512) cbA[j] = Ms[j];  // row 0 = column 0
    __syncthreads();
    float logacc = 0.f;
    for (int j = 0; j < D; j++) {
        float* __restrict__ cb = (j & 1) ? cbB : cbA;
        float* __restrict__ cn = (j & 1) ? cbA : cbB;
        if (tid == 0) {
            const float l = sqrtf(cb[j]);
            sh_l = l; sh_inv = 1.f / l;
            logacc += logf(l);
        }
        __syncthreads();
        const float inv = sh_inv;
        // scale column + store L^T row j
        for (int i = j + 1 + tid; i < D; i += 512) {
            const float v = cb[i] * inv;
            cb[i] = v;
            Ms[(size_t)j * D + i] = v;
        }
        if (tid == 0) Ms[(size_t)j * D + j] = sh_l;
        __syncthreads();
        if (j == D - 1) break;
        // rank-1 update of upper rows kk>j (cols i>=kk); extract col j+1 into cn
        for (int kk = j + 1 + wid; kk < D; kk += 8) {
            float* __restrict__ row = Ms + (size_t)kk * D;
            const float ck = cb[kk];
            const bool ex = (kk == j + 1);
            const int astart = (kk + 3) & ~3;
            for (int i = kk + lane; i < astart; i += 64) {
                const float v = row[i] - ck * cb[i];
                row[i] = v;
                if (ex) cn[i] = v;
            }
            for (int i = astart + 4 * lane; i < D; i += 256) {
                float4 a = *(float4*)&row[i];
                const float4 b = *(const float4*)&cb[i];
                a.x -= ck * b.x; a.y -= ck * b.y; a.z -= ck * b.z; a.w -= ck * b.w;
                *(float4*)&row[i] = a;
                if (ex) *(float4*)&cn[i] = a;
            }
        }
        __syncthreads();
    }
    if (tid == 0) logdet[s] = 2.f * logacc;
}

// ---------------- Kernel 5: invert 64x64 diagonal blocks of L (L stored ^T) ------
__global__ __launch_bounds__(64) void invdiag_kernel(const float* __restrict__ M,
                                                     float* __restrict__ invDT) {
    const int b = blockIdx.x, s = b >> 3, I = b & 7;
    const int c = threadIdx.x;
    __shared__ float Lsh[64 * 65];
    __shared__ float xsh[64 * 65];
    const float* __restrict__ Ms = M + (size_t)s * D * D;
    for (int e = c; e < 4096; e += 64) {
        const int i = e & 63, k = e >> 6;  // i fastest -> coalesced
        // L[I64+i][I64+k] = M[(I64+k)*D + I64+i]
        Lsh[i * 65 + k] = Ms[(size_t)(I * 64 + k) * D + I * 64 + i];
    }
    for (int i = 0; i < 64; i++) xsh[c * 65 + i] = (i == c) ? 1.f : 0.f;
    __syncthreads();
    for (int i = 0; i < 64; i++) {
        float t = xsh[c * 65 + i];
        for (int k = 0; k < i; k++) t -= Lsh[i * 65 + k] * xsh[c * 65 + k];
        xsh[c * 65 + i] = t / Lsh[i * 65 + i];
    }
    float* __restrict__ outp = invDT + (size_t)b * 4096 + c * 64;
    for (int i = 0; i < 64; i++) outp[i] = xsh[c * 65 + i];  // invDT[b][c][i] = invL[i][c]
}

// ---------------- Kernel 6: blocked trsm (z-panel in LDS) + maha + epilogue -----
// grid (32 n-panels, 64 s), 256 thr, dynamic LDS = (512*64 + 64*68)*4 = 145 KB
__global__ __launch_bounds__(256) void trsm_kernel(const float* __restrict__ M,
                                                   const float* __restrict__ invDT,
                                                   const float* __restrict__ x,
                                                   const float* __restrict__ mu,
                                                   const float* __restrict__ logdet,
                                                   float* __restrict__ out) {
    extern __shared__ float smem[];
    float* __restrict__ Z = smem;            // 512 x 64
    float* __restrict__ U = smem + D * 64;   // 64 x 68
    const int s = blockIdx.y;
    const int n0 = blockIdx.x * 64;
    const int tid = threadIdx.x;
    const int tx = tid & 15, ty = tid >> 4;
    const float* __restrict__ Ms = M + (size_t)s * D * D;
    const float* __restrict__ mus = mu + s * D;

    for (int I = 0; I < 8; I++) {
        float acc[4][4];
#pragma unroll
        for (int r = 0; r < 4; r++) {
            const int irow = I * 64 + 4 * ty + r;
            const float m0 = mus[irow];
#pragma unroll
            for (int q = 0; q < 4; q++)
                acc[r][q] = x[(size_t)(n0 + 4 * tx + q) * D + irow] - m0;
        }
        for (int J = 0; J < I; J++) {
            __syncthreads();
            for (int e = tid; e < 4096; e += 256) {
                const int k = e >> 6, i = e & 63;
                // U[k][i] = L[I64+i][J64+k] = M[(J64+k)*D + I64+i]  (coalesced)
                U[k * 68 + i] = Ms[(size_t)(J * 64 + k) * D + I * 64 + i];
            }
            __syncthreads();
#pragma unroll 4
            for (int k = 0; k < 64; k++) {
                const float4 a = *(const float4*)&U[k * 68 + 4 * ty];
                const float4 b = *(const float4*)&Z[(J * 64 + k) * 64 + 4 * tx];
                const float av[4] = {a.x, a.y, a.z, a.w};
                const float bv[4] = {b.x, b.y, b.z, b.w};
#pragma unroll
                for (int r = 0; r < 4; r++)
#pragma unroll
                    for (int q = 0; q < 4; q++) acc[r][q] -= av[r] * bv[q];
            }
        }
        __syncthreads();
#pragma unroll
        for (int r = 0; r < 4; r++) {
            float4 v4;
            v4.x = acc[r][0]; v4.y = acc[r][1]; v4.z = acc[r][2]; v4.w = acc[r][3];
            *(float4*)&U[(4 * ty + r) * 68 + 4 * tx] = v4;
        }
        __syncthreads();
        {
            float zacc[4][4];
#pragma unroll
            for (int r = 0; r < 4; r++)
#pragma unroll
                for (int q = 0; q < 4; q++) zacc[r][q] = 0.f;
            const float* __restrict__ iD = invDT + (size_t)(s * 8 + I) * 4096;
#pragma unroll 4
            for (int k = 0; k < 64; k++) {
                const float4 a = *(const float4*)&iD[k * 64 + 4 * ty];
                const float4 b = *(const float4*)&U[k * 68 + 4 * tx];
                const float av[4] = {a.x, a.y, a.z, a.w};
                const float bv[4] = {b.x, b.y, b.z, b.w};
#pragma unroll
                for (int r = 0; r < 4; r++)
#pragma unroll
                    for (int q = 0; q < 4; q++) zacc[r][q] += av[r] * bv[q];
            }
#pragma unroll
            for (int r = 0; r < 4; r++) {
                float4 v4;
                v4.x = zacc[r][0]; v4.y = zacc[r][1]; v4.z = zacc[r][2]; v4.w = zacc[r][3];
                *(float4*)&Z[(I * 64 + 4 * ty + r) * 64 + 4 * tx] = v4;
            }
        }
    }
    __syncthreads();
    {
        const int c = tid & 63, part = tid >> 6;
        float sum = 0.f;
        for (int i = part * 128; i < part * 128 + 128; i++) {
            const float z = Z[i * 64 + c];
            sum += z * z;
        }
        U[part * 64 + c] = sum;
    }
    __syncthreads();
    if (tid < 64) {
        const float mah = U[tid] + U[64 + tid] + U[128 + tid] + U[192 + tid];
        out[(size_t)(n0 + tid) * 64 + s] = -0.5f * (mah + logdet[s] + 940.993058f);
    }
}

extern "C" void kernel_launch(void* const* d_in, const int* in_sizes, int n_in,
                              void* d_out, int out_size, void* d_ws, size_t ws_size,
                              hipStream_t stream) {
    const float* x  = (const float*)d_in[0];   // (2048, 512)
    const float* mu = (const float*)d_in[1];   // (64, 1, 512)
    const float* sp = (const float*)d_in[3];   // (64, 1, 512, 512)
    float* out = (float*)d_out;                // (2048, 64) fp32

    float* wsf  = (float*)d_ws;
    float* Mw   = wsf;                              // 64*512*512
    float* Tw   = wsf + (size_t)16777216;           // 64*512*512
    float* dvec = wsf + (size_t)33554432;
    float* evec = dvec + 32768;
    float* lamv = evec + 32768;
    float* logd = lamv + 32768;
    float* invDT = Tw;                              // Tw dead after bisect

    syrk_kernel<<<dim3(64, 64), dim3(256), 0, stream>>>(sp, Mw, Tw);
    tridiag_kernel<<<dim3(64), dim3(1024), 0, stream>>>(Tw, dvec, evec);
    bisect_kernel<<<dim3(64), dim3(512), 0, stream>>>(dvec, evec, lamv);
    chol_kernel<<<dim3(64), dim3(512), 0, stream>>>(Mw, lamv, logd);
    invdiag_kernel<<<dim3(512), dim3(64), 0, stream>>>(Mw, invDT);
    const size_t lds = (size_t)(D * 64 + 64 * 68) * sizeof(float);
    trsm_kernel<<<dim3(32, 64), dim3(256), lds, stream>>>(Mw, invDT, x, mu, logd, out);
}

// Round 3
// 14119.032 us; speedup vs baseline: 4.6420x; 1.6837x over previous
//
#include <hip/hip_runtime.h>

#define D 512
#define TW 16

__device__ __forceinline__ float waveSum(float v) {
#pragma unroll
    for (int m = 32; m > 0; m >>= 1) v += __shfl_xor(v, m, 64);
    return v;
}
__device__ __forceinline__ float waveMin(float v) {
#pragma unroll
    for (int m = 32; m > 0; m >>= 1) v = fminf(v, __shfl_xor(v, m, 64));
    return v;
}
__device__ __forceinline__ float waveMax(float v) {
#pragma unroll
    for (int m = 32; m > 0; m >>= 1) v = fmaxf(v, __shfl_xor(v, m, 64));
    return v;
}

// ---------------- Kernel 1: m = A^T A (per s). grid (64 tiles, 64 s), 256 thr ----
__global__ __launch_bounds__(256) void syrk_kernel(const float* __restrict__ sp,
                                                   float* __restrict__ M) {
    const int s = blockIdx.y;
    const int I = blockIdx.x >> 3, J = blockIdx.x & 7;
    const int tx = threadIdx.x & 15, ty = threadIdx.x >> 4;
    const float* __restrict__ A = sp + (size_t)s * D * D;
    __shared__ __align__(16) float As[64 * 68];
    __shared__ __align__(16) float Bs[64 * 68];
    float acc[4][4];
#pragma unroll
    for (int r = 0; r < 4; r++)
#pragma unroll
        for (int q = 0; q < 4; q++) acc[r][q] = 0.f;

    for (int k0 = 0; k0 < D; k0 += 64) {
        for (int e = threadIdx.x; e < 4096; e += 256) {
            const int col = e & 63, kr = e >> 6;
            As[kr * 68 + col] = A[(size_t)(k0 + kr) * D + I * 64 + col];
            Bs[kr * 68 + col] = A[(size_t)(k0 + kr) * D + J * 64 + col];
        }
        __syncthreads();
#pragma unroll 4
        for (int k = 0; k < 64; k++) {
            const float4 a = *(const float4*)&As[k * 68 + 4 * ty];
            const float4 b = *(const float4*)&Bs[k * 68 + 4 * tx];
            const float av[4] = {a.x, a.y, a.z, a.w};
            const float bv[4] = {b.x, b.y, b.z, b.w};
#pragma unroll
            for (int r = 0; r < 4; r++)
#pragma unroll
                for (int q = 0; q < 4; q++) acc[r][q] += av[r] * bv[q];
        }
        __syncthreads();
    }
#pragma unroll
    for (int r = 0; r < 4; r++) {
        float4 v4;
        v4.x = acc[r][0]; v4.y = acc[r][1]; v4.z = acc[r][2]; v4.w = acc[r][3];
        const size_t off = (size_t)s * D * D + (size_t)(I * 64 + 4 * ty + r) * D + J * 64 + 4 * tx;
        *(float4*)(M + off) = v4;
    }
}

// ---------------- Kernel 2a: LATRD panel (nb<=32). 64 WGs x 1024 thr ------------
// LDS: Vs/Ws row-major stride 33; vb/pf; c1/c2; red; sca[beta, c, skip]
__global__ __launch_bounds__(1024) void latrd_panel(float* __restrict__ T,
                                                    float* __restrict__ Vt,
                                                    float* __restrict__ Wt,
                                                    float* __restrict__ dvec,
                                                    float* __restrict__ evec,
                                                    int ps, int jmax) {
    const int s = blockIdx.x;
    float* __restrict__ Ts = T + (size_t)s * D * D;
    float* __restrict__ Vg = Vt + (size_t)s * 32 * D;
    float* __restrict__ Wg = Wt + (size_t)s * 32 * D;
    const int tid = threadIdx.x, lane = tid & 63, wid = tid >> 6;
    extern __shared__ float sm[];
    float* __restrict__ Vs = sm;              // 512*33
    float* __restrict__ Ws = sm + 16896;      // 512*33
    float* __restrict__ vb = sm + 33792;      // 512
    float* __restrict__ pf = sm + 34304;      // 512
    float* __restrict__ c1 = sm + 34816;      // 32
    float* __restrict__ c2 = sm + 34848;      // 32
    float* __restrict__ red = sm + 34880;     // 16
    float* __restrict__ sca = sm + 34896;     // 4

    for (int i = tid; i < 34304; i += 1024) sm[i] = 0.f;  // Vs, Ws, vb
    __syncthreads();

    for (int j = 0; j < jmax; j++) {
        const int k = ps + j, sup = k + 1;
        // ---- S1: build corrected pivot row -> vb ----
        for (int i = sup + tid; i < D; i += 1024) {
            float corr = 0.f;
            for (int t = 0; t < j; t++)
                corr += Vs[(size_t)i * 33 + t] * Ws[(size_t)k * 33 + t]
                      + Ws[(size_t)i * 33 + t] * Vs[(size_t)k * 33 + t];
            vb[i] = Ts[(size_t)k * D + i] - corr;
        }
        if (tid == 0) {
            float dc = 0.f;
            for (int t = 0; t < j; t++) dc += Vs[(size_t)k * 33 + t] * Ws[(size_t)k * 33 + t];
            dvec[s * D + k] = Ts[(size_t)k * D + k] - 2.f * dc;
            vb[k] = 0.f;  // zero stale slot
        }
        __syncthreads();
        // ---- S2: xn2 partials + c1 = W^T v, c2 = V^T v (over i > sup) ----
        {
            float xp = 0.f;
            for (int i = sup + 1 + tid; i < D; i += 1024) xp += vb[i] * vb[i];
            xp = waveSum(xp);
            if (lane == 0) red[wid] = xp;
            const int t = tid >> 5, r = tid & 31;
            float a1 = 0.f, a2 = 0.f;
            for (int i = sup + 1 + r; i < D; i += 32) {
                const float v = vb[i];
                a1 += Ws[(size_t)i * 33 + t] * v;
                a2 += Vs[(size_t)i * 33 + t] * v;
            }
#pragma unroll
            for (int m = 16; m > 0; m >>= 1) {
                a1 += __shfl_xor(a1, m, 64);
                a2 += __shfl_xor(a2, m, 64);
            }
            if (r == 0) { c1[t] = a1; c2[t] = a2; }
        }
        __syncthreads();
        // ---- F1: wave0 finalize (beta, v0), add v0 term into c1/c2 ----
        if (wid == 0) {
            float xn2 = (lane < TW) ? red[lane] : 0.f;
            xn2 = waveSum(xn2);
            const float a0 = vb[sup];
            float beta = 0.f, v0 = 0.f;
            int skip = 0;
            if (lane == 0) {
                if (xn2 <= 0.f) {
                    skip = 1;
                    evec[s * D + k] = a0;
                } else {
                    const float an = sqrtf(a0 * a0 + xn2);
                    const float al = (a0 >= 0.f) ? -an : an;
                    v0 = a0 - al;
                    beta = 2.f / (v0 * v0 + xn2);
                    evec[s * D + k] = al;
                    vb[sup] = v0;
                }
                sca[0] = beta; sca[2] = (float)skip;
            }
            v0 = __shfl(v0, 0, 64);
            skip = __shfl(skip, 0, 64);
            if (!skip) {
                if (lane < 32) c1[lane] += Ws[(size_t)sup * 33 + lane] * v0;
                else           c2[lane - 32] += Vs[(size_t)sup * 33 + (lane - 32)] * v0;
            }
        }
        __syncthreads();
        const float beta = sca[0];
        if (sca[2] != 0.f) {
            for (int i = sup + tid; i < D; i += 1024) { Vg[j * D + i] = 0.f; Wg[j * D + i] = 0.f; }
            __syncthreads();
            continue;
        }
        // ---- S3': symv + corrections + pv partials ----
        {
            const int w0 = sup & ~15;
            float pvw = 0.f;
            for (int i = sup + wid; i < D; i += TW) {
                const float* __restrict__ row = Ts + (size_t)i * D;
                float part = 0.f;
                for (int cc = w0 + 4 * lane; cc < D; cc += 256) {
                    const float4 a = *(const float4*)&row[cc];
                    const float4 b = *(const float4*)&vb[cc];
                    part += a.x * b.x + a.y * b.y + a.z * b.z + a.w * b.w;
                }
                part -= (lane < 32) ? Vs[(size_t)i * 33 + lane] * c1[lane]
                                    : Ws[(size_t)i * 33 + (lane - 32)] * c2[lane - 32];
                part = waveSum(part);
                if (lane == 0) {
                    const float p = beta * part;
                    pf[i] = p;
                    pvw += p * vb[i];
                }
            }
            if (lane == 0) red[wid] = pvw;
        }
        __syncthreads();
        if (tid == 0) {
            float pv = 0.f;
            for (int q = 0; q < TW; q++) pv += red[q];
            sca[1] = 0.5f * beta * pv;
        }
        __syncthreads();
        // ---- S5: w = p - c*v; store V/W col j (LDS + global t-major) ----
        {
            const float cc = sca[1];
            for (int i = sup + tid; i < D; i += 1024) {
                const float v = vb[i];
                const float w = pf[i] - cc * v;
                Vs[(size_t)i * 33 + j] = v;
                Ws[(size_t)i * 33 + j] = w;
                Vg[j * D + i] = v;
                Wg[j * D + i] = w;
            }
        }
        __syncthreads();
    }
    // ---- last panel: finalize trailing 2x2 ----
    if (ps + jmax == D - 2 && tid == 0) {
        const int k1 = D - 2, k2 = D - 1;
        float dc = 0.f, ec = 0.f, dc2 = 0.f;
        for (int t = 0; t < jmax; t++) {
            dc  += Vs[(size_t)k1 * 33 + t] * Ws[(size_t)k1 * 33 + t];
            ec  += Vs[(size_t)k1 * 33 + t] * Ws[(size_t)k2 * 33 + t]
                 + Ws[(size_t)k1 * 33 + t] * Vs[(size_t)k2 * 33 + t];
            dc2 += Vs[(size_t)k2 * 33 + t] * Ws[(size_t)k2 * 33 + t];
        }
        dvec[s * D + k1] = Ts[(size_t)k1 * D + k1] - 2.f * dc;
        evec[s * D + k1] = Ts[(size_t)k1 * D + k2] - ec;
        dvec[s * D + k2] = Ts[(size_t)k2 * D + k2] - 2.f * dc2;
        evec[s * D + k2] = 0.f;
    }
}

// ---------------- Kernel 2b: rank-64 symmetric update A -= V W^T + W V^T --------
// grid (nt, nt, 64 s), 256 thr, 64x64 tile, K=32
__global__ __launch_bounds__(256) void latrd_update(float* __restrict__ T,
                                                    const float* __restrict__ Vt,
                                                    const float* __restrict__ Wt,
                                                    int r0) {
    const int s = blockIdx.z;
    const int i0 = r0 + 64 * blockIdx.y;
    const int j0 = r0 + 64 * blockIdx.x;
    float* __restrict__ Ts = T + (size_t)s * D * D;
    const float* __restrict__ Vg = Vt + (size_t)s * 32 * D;
    const float* __restrict__ Wg = Wt + (size_t)s * 32 * D;
    __shared__ __align__(16) float Vi[32 * 68], Wi[32 * 68], Vj[32 * 68], Wj[32 * 68];
    const int tid = threadIdx.x, tx = tid & 15, ty = tid >> 4;
    const float4 z4 = {0.f, 0.f, 0.f, 0.f};
    for (int e = tid; e < 512; e += 256) {
        const int t = e >> 4, c4 = (e & 15) * 4;
        const int gi = i0 + c4, gj = j0 + c4;
        *(float4*)&Vi[t * 68 + c4] = (gi < D) ? *(const float4*)&Vg[t * D + gi] : z4;
        *(float4*)&Wi[t * 68 + c4] = (gi < D) ? *(const float4*)&Wg[t * D + gi] : z4;
        *(float4*)&Vj[t * 68 + c4] = (gj < D) ? *(const float4*)&Vg[t * D + gj] : z4;
        *(float4*)&Wj[t * 68 + c4] = (gj < D) ? *(const float4*)&Wg[t * D + gj] : z4;
    }
    __syncthreads();
    float acc[4][4] = {{0.f}};
#pragma unroll 4
    for (int t = 0; t < 32; t++) {
        const float4 va = *(const float4*)&Vi[t * 68 + 4 * ty];
        const float4 wa = *(const float4*)&Wi[t * 68 + 4 * ty];
        const float4 vc = *(const float4*)&Vj[t * 68 + 4 * tx];
        const float4 wc = *(const float4*)&Wj[t * 68 + 4 * tx];
        const float av[4] = {va.x, va.y, va.z, va.w};
        const float aw[4] = {wa.x, wa.y, wa.z, wa.w};
        const float bv[4] = {vc.x, vc.y, vc.z, vc.w};
        const float bw[4] = {wc.x, wc.y, wc.z, wc.w};
#pragma unroll
        for (int r = 0; r < 4; r++)
#pragma unroll
            for (int q = 0; q < 4; q++) acc[r][q] += av[r] * bw[q] + aw[r] * bv[q];
    }
    const int gj = j0 + 4 * tx;
    if (gj >= D) return;
#pragma unroll
    for (int r = 0; r < 4; r++) {
        const int gi = i0 + 4 * ty + r;
        if (gi >= D) continue;
        float4 c = *(float4*)&Ts[(size_t)gi * D + gj];
        c.x -= acc[r][0]; c.y -= acc[r][1]; c.z -= acc[r][2]; c.w -= acc[r][3];
        *(float4*)&Ts[(size_t)gi * D + gj] = c;
    }
}

// ---------------- Kernel 3: bisection eigenvalues (ascending). grid 64, 512 thr --
__global__ __launch_bounds__(512) void bisect_kernel(const float* __restrict__ dvec,
                                                     const float* __restrict__ evec,
                                                     float* __restrict__ lam) {
    const int s = blockIdx.x, tid = threadIdx.x;
    const int lane = tid & 63, wid = tid >> 6;
    __shared__ float d[D], e2[D], ea[D];
    __shared__ float red[8];
    __shared__ float sh_lo, sh_hi;
    {
        const float dv = dvec[s * D + tid];
        const float ev = evec[s * D + tid];
        d[tid] = dv; ea[tid] = fabsf(ev); e2[tid] = ev * ev;
    }
    __syncthreads();
    const float rad = ea[tid] + ((tid > 0) ? ea[tid - 1] : 0.f);
    float lo = waveMin(d[tid] - rad);
    float hi = waveMax(d[tid] + rad);
    if (lane == 0) red[wid] = lo;
    __syncthreads();
    if (tid == 0) {
        float t = red[0];
        for (int q = 1; q < 8; q++) t = fminf(t, red[q]);
        sh_lo = t - 1e-3f * fmaxf(fabsf(t), 1.f);
    }
    __syncthreads();
    if (lane == 0) red[wid] = hi;
    __syncthreads();
    if (tid == 0) {
        float t = red[0];
        for (int q = 1; q < 8; q++) t = fmaxf(t, red[q]);
        sh_hi = t + 1e-3f * fmaxf(fabsf(t), 1.f);
    }
    __syncthreads();
    float a = sh_lo, b = sh_hi;
    const int j1 = tid + 1;
    for (int it = 0; it < 36; it++) {
        const float mid = 0.5f * (a + b);
        int cnt = 0;
        float q = d[0] - mid;
        cnt += (q < 0.f);
        for (int i = 1; i < D; i++) {
            float den = q;
            const float ad = fabsf(den);
            den = (ad < 1e-26f) ? ((den < 0.f) ? -1e-26f : 1e-26f) : den;
            q = d[i] - mid - e2[i - 1] / den;
            cnt += (q < 0.f);
        }
        if (cnt >= j1) b = mid; else a = mid;
    }
    lam[s * D + tid] = 0.5f * (a + b);
}

// ---------------- Kernel 4a: Cholesky panel (upper storage, L^T rows) -----------
// 64 WGs x 256 thr. Panel rows [j0, j0+32), cols [j0, 512) in LDS; 0.01*lam added
// at load for the panel's own diag. Writes L^T rows back + compact Lp (t-major).
__global__ __launch_bounds__(256) void chol_panel(float* __restrict__ M,
                                                  const float* __restrict__ lam,
                                                  float* __restrict__ logdet,
                                                  float* __restrict__ Lp,
                                                  int j0, int first) {
    const int s = blockIdx.x;
    float* __restrict__ Ms = M + (size_t)s * D * D;
    float* __restrict__ Lps = Lp + (size_t)s * 32 * D;
    const int tid = threadIdx.x, lane = tid & 63, wid = tid >> 6;
    extern __shared__ float smc[];
    float* __restrict__ P = smc;          // 32*520
    const int Wd = D - j0;
    for (int e = tid; e < 32 * D; e += 256) {
        const int t = e >> 9, i = e & 511;
        if (i >= j0) {
            const int il = i - j0;
            float v = Ms[(size_t)(j0 + t) * D + i];
            if (il == t) v += 0.01f * lam[s * D + j0 + t];
            P[t * 520 + il] = v;
        }
    }
    __syncthreads();
    float lacc = 0.f;
    for (int jl = 0; jl < 32; jl++) {
        const float pd = P[jl * 520 + jl];
        const float inv = 1.f / sqrtf(pd);
        if (tid == 0) { lacc += 0.5f * logf(pd); P[jl * 520 + jl] = sqrtf(pd); }
        for (int il = jl + 1 + tid; il < Wd; il += 256) P[jl * 520 + il] *= inv;
        __syncthreads();
        for (int kk = jl + 1 + wid; kk < 32; kk += 4) {
            const float f = P[jl * 520 + kk];
            for (int il = kk + lane; il < Wd; il += 64) P[kk * 520 + il] -= f * P[jl * 520 + il];
        }
        __syncthreads();
    }
    if (tid == 0) logdet[s] = (first ? 0.f : logdet[s]) + 2.f * lacc;
    for (int e = tid; e < 32 * D; e += 256) {
        const int t = e >> 9, i = e & 511;
        const int il = i - j0;
        if (il >= t) Ms[(size_t)(j0 + t) * D + i] = P[t * 520 + il];
        if (i >= j0 + 32) Lps[(size_t)t * D + i] = P[t * 520 + il];
    }
}

// ---------------- Kernel 4b: chol trailing update C -= Lp^T-outer (rank 32) -----
__global__ __launch_bounds__(256) void chol_update(float* __restrict__ M,
                                                   const float* __restrict__ Lp,
                                                   int r0) {
    if (blockIdx.x < blockIdx.y) return;  // upper tiles only (col-tile >= row-tile)
    const int s = blockIdx.z;
    const int i0 = r0 + 64 * blockIdx.y;
    const int j0 = r0 + 64 * blockIdx.x;
    float* __restrict__ Ms = M + (size_t)s * D * D;
    const float* __restrict__ Lps = Lp + (size_t)s * 32 * D;
    __shared__ __align__(16) float Li[32 * 68], Lj[32 * 68];
    const int tid = threadIdx.x, tx = tid & 15, ty = tid >> 4;
    const float4 z4 = {0.f, 0.f, 0.f, 0.f};
    for (int e = tid; e < 512; e += 256) {
        const int t = e >> 4, c4 = (e & 15) * 4;
        const int gi = i0 + c4, gj = j0 + c4;
        *(float4*)&Li[t * 68 + c4] = (gi < D) ? *(const float4*)&Lps[(size_t)t * D + gi] : z4;
        *(float4*)&Lj[t * 68 + c4] = (gj < D) ? *(const float4*)&Lps[(size_t)t * D + gj] : z4;
    }
    __syncthreads();
    float acc[4][4] = {{0.f}};
#pragma unroll 4
    for (int t = 0; t < 32; t++) {
        const float4 a = *(const float4*)&Li[t * 68 + 4 * ty];
        const float4 b = *(const float4*)&Lj[t * 68 + 4 * tx];
        const float av[4] = {a.x, a.y, a.z, a.w};
        const float bv[4] = {b.x, b.y, b.z, b.w};
#pragma unroll
        for (int r = 0; r < 4; r++)
#pragma unroll
            for (int q = 0; q < 4; q++) acc[r][q] += av[r] * bv[q];
    }
    const int gj = j0 + 4 * tx;
    if (gj >= D) return;
#pragma unroll
    for (int r = 0; r < 4; r++) {
        const int gi = i0 + 4 * ty + r;
        if (gi >= D) continue;
        float4 c = *(float4*)&Ms[(size_t)gi * D + gj];
        c.x -= acc[r][0]; c.y -= acc[r][1]; c.z -= acc[r][2]; c.w -= acc[r][3];
        *(float4*)&Ms[(size_t)gi * D + gj] = c;
    }
}

// ---------------- Kernel 5: invert 64x64 diagonal blocks of L (L stored ^T) ------
__global__ __launch_bounds__(64) void invdiag_kernel(const float* __restrict__ M,
                                                     float* __restrict__ invDT) {
    const int b = blockIdx.x, s = b >> 3, I = b & 7;
    const int c = threadIdx.x;
    __shared__ float Lsh[64 * 65];
    __shared__ float xsh[64 * 65];
    const float* __restrict__ Ms = M + (size_t)s * D * D;
    for (int e = c; e < 4096; e += 64) {
        const int i = e & 63, k = e >> 6;
        Lsh[i * 65 + k] = Ms[(size_t)(I * 64 + k) * D + I * 64 + i];
    }
    for (int i = 0; i < 64; i++) xsh[c * 65 + i] = (i == c) ? 1.f : 0.f;
    __syncthreads();
    for (int i = 0; i < 64; i++) {
        float t = xsh[c * 65 + i];
        for (int k = 0; k < i; k++) t -= Lsh[i * 65 + k] * xsh[c * 65 + k];
        xsh[c * 65 + i] = t / Lsh[i * 65 + i];
    }
    float* __restrict__ outp = invDT + (size_t)b * 4096 + c * 64;
    for (int i = 0; i < 64; i++) outp[i] = xsh[c * 65 + i];
}

// ---------------- Kernel 6: blocked trsm (z-panel in LDS) + maha + epilogue -----
__global__ __launch_bounds__(256) void trsm_kernel(const float* __restrict__ M,
                                                   const float* __restrict__ invDT,
                                                   const float* __restrict__ x,
                                                   const float* __restrict__ mu,
                                                   const float* __restrict__ logdet,
                                                   float* __restrict__ out) {
    extern __shared__ float smem[];
    float* __restrict__ Z = smem;            // 512 x 64
    float* __restrict__ U = smem + D * 64;   // 64 x 68
    const int s = blockIdx.y;
    const int n0 = blockIdx.x * 64;
    const int tid = threadIdx.x;
    const int tx = tid & 15, ty = tid >> 4;
    const float* __restrict__ Ms = M + (size_t)s * D * D;
    const float* __restrict__ mus = mu + s * D;

    for (int I = 0; I < 8; I++) {
        float acc[4][4];
#pragma unroll
        for (int r = 0; r < 4; r++) {
            const int irow = I * 64 + 4 * ty + r;
            const float m0 = mus[irow];
#pragma unroll
            for (int q = 0; q < 4; q++)
                acc[r][q] = x[(size_t)(n0 + 4 * tx + q) * D + irow] - m0;
        }
        for (int J = 0; J < I; J++) {
            __syncthreads();
            for (int e = tid; e < 4096; e += 256) {
                const int k = e >> 6, i = e & 63;
                U[k * 68 + i] = Ms[(size_t)(J * 64 + k) * D + I * 64 + i];
            }
            __syncthreads();
#pragma unroll 4
            for (int k = 0; k < 64; k++) {
                const float4 a = *(const float4*)&U[k * 68 + 4 * ty];
                const float4 b = *(const float4*)&Z[(J * 64 + k) * 64 + 4 * tx];
                const float av[4] = {a.x, a.y, a.z, a.w};
                const float bv[4] = {b.x, b.y, b.z, b.w};
#pragma unroll
                for (int r = 0; r < 4; r++)
#pragma unroll
                    for (int q = 0; q < 4; q++) acc[r][q] -= av[r] * bv[q];
            }
        }
        __syncthreads();
#pragma unroll
        for (int r = 0; r < 4; r++) {
            float4 v4;
            v4.x = acc[r][0]; v4.y = acc[r][1]; v4.z = acc[r][2]; v4.w = acc[r][3];
            *(float4*)&U[(4 * ty + r) * 68 + 4 * tx] = v4;
        }
        __syncthreads();
        {
            float zacc[4][4];
#pragma unroll
            for (int r = 0; r < 4; r++)
#pragma unroll
                for (int q = 0; q < 4; q++) zacc[r][q] = 0.f;
            const float* __restrict__ iD = invDT + (size_t)(s * 8 + I) * 4096;
#pragma unroll 4
            for (int k = 0; k < 64; k++) {
                const float4 a = *(const float4*)&iD[k * 64 + 4 * ty];
                const float4 b = *(const float4*)&U[k * 68 + 4 * tx];
                const float av[4] = {a.x, a.y, a.z, a.w};
                const float bv[4] = {b.x, b.y, b.z, b.w};
#pragma unroll
                for (int r = 0; r < 4; r++)
#pragma unroll
                    for (int q = 0; q < 4; q++) zacc[r][q] += av[r] * bv[q];
            }
#pragma unroll
            for (int r = 0; r < 4; r++) {
                float4 v4;
                v4.x = zacc[r][0]; v4.y = zacc[r][1]; v4.z = zacc[r][2]; v4.w = zacc[r][3];
                *(float4*)&Z[(I * 64 + 4 * ty + r) * 64 + 4 * tx] = v4;
            }
        }
    }
    __syncthreads();
    {
        const int c = tid & 63, part = tid >> 6;
        float sum = 0.f;
        for (int i = part * 128; i < part * 128 + 128; i++) {
            const float z = Z[i * 64 + c];
            sum += z * z;
        }
        U[part * 64 + c] = sum;
    }
    __syncthreads();
    if (tid < 64) {
        const float mah = U[tid] + U[64 + tid] + U[128 + tid] + U[192 + tid];
        out[(size_t)(n0 + tid) * 64 + s] = -0.5f * (mah + logdet[s] + 940.993058f);
    }
}

extern "C" void kernel_launch(void* const* d_in, const int* in_sizes, int n_in,
                              void* d_out, int out_size, void* d_ws, size_t ws_size,
                              hipStream_t stream) {
    const float* x  = (const float*)d_in[0];   // (2048, 512)
    const float* mu = (const float*)d_in[1];   // (64, 1, 512)
    const float* sp = (const float*)d_in[3];   // (64, 1, 512, 512)
    float* out = (float*)d_out;                // (2048, 64) fp32

    float* wsf  = (float*)d_ws;
    float* MT   = wsf;                          // 64*512*512 = 16,777,216 floats
    float* dvec = wsf + (size_t)16777216;       // 32768
    float* evec = dvec + 32768;
    float* lamv = evec + 32768;
    float* logd = lamv + 32768;                 // 64
    float* Vt   = logd + 64;                    // 64*32*512 = 1,048,576
    float* Wt   = Vt + (size_t)1048576;         // 1,048,576
    float* Lp   = Vt;                           // reuse (chol after tridiag)
    float* invDT = Vt;                          // reuse (invdiag after chol), 2M floats

    // 1) m = A^T A
    syrk_kernel<<<dim3(64, 64), dim3(256), 0, stream>>>(sp, MT);

    // 2) blocked LATRD tridiagonalization
    const size_t plds = (size_t)34900 * sizeof(float);
    for (int p = 0; p < 16; p++) {
        const int ps = 32 * p;
        const int jmax = (p == 15) ? 30 : 32;
        latrd_panel<<<dim3(64), dim3(1024), plds, stream>>>(MT, Vt, Wt, dvec, evec, ps, jmax);
        if (p < 15) {
            const int r0 = ps + 32;
            const int nt = (D - r0 + 63) / 64;
            latrd_update<<<dim3(nt, nt, 64), dim3(256), 0, stream>>>(MT, Vt, Wt, r0);
        }
    }

    // 3) all eigenvalues via Sturm bisection
    bisect_kernel<<<dim3(64), dim3(512), 0, stream>>>(dvec, evec, lamv);

    // 4) rebuild m (tridiag destroyed it), then blocked Cholesky of sigma
    syrk_kernel<<<dim3(64, 64), dim3(256), 0, stream>>>(sp, MT);
    const size_t clds = (size_t)(32 * 520 + 4) * sizeof(float);
    for (int p = 0; p < 16; p++) {
        const int j0 = 32 * p;
        chol_panel<<<dim3(64), dim3(256), clds, stream>>>(MT, lamv, logd, Lp, j0, p == 0 ? 1 : 0);
        if (p < 15) {
            const int r0 = j0 + 32;
            const int nt = (D - r0 + 63) / 64;
            chol_update<<<dim3(nt, nt, 64), dim3(256), 0, stream>>>(MT, Lp, r0);
        }
    }

    // 5) invert diagonal 64x64 blocks of L
    invdiag_kernel<<<dim3(512), dim3(64), 0, stream>>>(MT, invDT);

    // 6) blocked trsm + mahalanobis + epilogue
    const size_t tlds = (size_t)(D * 64 + 64 * 68) * sizeof(float);
    trsm_kernel<<<dim3(32, 64), dim3(256), tlds, stream>>>(MT, invDT, x, mu, logd, out);
}

// Round 4
// 12002.154 us; speedup vs baseline: 5.4607x; 1.1764x over previous
//
#include <hip/hip_runtime.h>

#define D 512
#define TW 16

__device__ __forceinline__ float waveSum(float v) {
#pragma unroll
    for (int m = 32; m > 0; m >>= 1) v += __shfl_xor(v, m, 64);
    return v;
}
__device__ __forceinline__ float waveMin(float v) {
#pragma unroll
    for (int m = 32; m > 0; m >>= 1) v = fminf(v, __shfl_xor(v, m, 64));
    return v;
}
__device__ __forceinline__ float waveMax(float v) {
#pragma unroll
    for (int m = 32; m > 0; m >>= 1) v = fmaxf(v, __shfl_xor(v, m, 64));
    return v;
}

// ---------------- Kernel 0: xT[d][n] = x[n][d]. grid (32, 8), 256 thr ----------
__global__ __launch_bounds__(256) void xpose_kernel(const float* __restrict__ x,
                                                    float* __restrict__ xT) {
    __shared__ float t[64][65];
    const int bx = blockIdx.x * 64;  // n block
    const int by = blockIdx.y * 64;  // d block
    const int tid = threadIdx.x;
    const int lx = tid & 63, lq = tid >> 6;
#pragma unroll
    for (int r = 0; r < 64; r += 4)
        t[r + lq][lx] = x[(size_t)(bx + r + lq) * D + by + lx];
    __syncthreads();
#pragma unroll
    for (int r = 0; r < 64; r += 4)
        xT[(size_t)(by + r + lq) * 2048 + bx + lx] = t[lx][r + lq];
}

// ---------------- Kernel 1: m = A^T A (per s). grid (64 tiles, 64 s), 256 thr ----
__global__ __launch_bounds__(256) void syrk_kernel(const float* __restrict__ sp,
                                                   float* __restrict__ M) {
    const int s = blockIdx.y;
    const int I = blockIdx.x >> 3, J = blockIdx.x & 7;
    const int tx = threadIdx.x & 15, ty = threadIdx.x >> 4;
    const float* __restrict__ A = sp + (size_t)s * D * D;
    __shared__ __align__(16) float As[64 * 68];
    __shared__ __align__(16) float Bs[64 * 68];
    float acc[4][4];
#pragma unroll
    for (int r = 0; r < 4; r++)
#pragma unroll
        for (int q = 0; q < 4; q++) acc[r][q] = 0.f;

    for (int k0 = 0; k0 < D; k0 += 64) {
        for (int e = threadIdx.x; e < 4096; e += 256) {
            const int col = e & 63, kr = e >> 6;
            As[kr * 68 + col] = A[(size_t)(k0 + kr) * D + I * 64 + col];
            Bs[kr * 68 + col] = A[(size_t)(k0 + kr) * D + J * 64 + col];
        }
        __syncthreads();
#pragma unroll 4
        for (int k = 0; k < 64; k++) {
            const float4 a = *(const float4*)&As[k * 68 + 4 * ty];
            const float4 b = *(const float4*)&Bs[k * 68 + 4 * tx];
            const float av[4] = {a.x, a.y, a.z, a.w};
            const float bv[4] = {b.x, b.y, b.z, b.w};
#pragma unroll
            for (int r = 0; r < 4; r++)
#pragma unroll
                for (int q = 0; q < 4; q++) acc[r][q] += av[r] * bv[q];
        }
        __syncthreads();
    }
#pragma unroll
    for (int r = 0; r < 4; r++) {
        float4 v4;
        v4.x = acc[r][0]; v4.y = acc[r][1]; v4.z = acc[r][2]; v4.w = acc[r][3];
        const size_t off = (size_t)s * D * D + (size_t)(I * 64 + 4 * ty + r) * D + J * 64 + 4 * tx;
        *(float4*)(M + off) = v4;
    }
}

// ---------------- Kernel 2a: LATRD panel v2. 64 WGs x 1024 thr ------------------
// 4 barriers/column, no serial thread-0 phases, quarter-wave symv, register
// prefetch of next pivot row. Vs/Ws stride 33 in LDS.
__global__ __launch_bounds__(1024) void latrd_panel(float* __restrict__ T,
                                                    float* __restrict__ Vt,
                                                    float* __restrict__ Wt,
                                                    float* __restrict__ dvec,
                                                    float* __restrict__ evec,
                                                    int ps, int jmax) {
    const int s = blockIdx.x;
    float* __restrict__ Ts = T + (size_t)s * D * D;
    float* __restrict__ Vg = Vt + (size_t)s * 32 * D;
    float* __restrict__ Wg = Wt + (size_t)s * 32 * D;
    const int tid = threadIdx.x, lane = tid & 63, wid = tid >> 6;
    const int l4 = lane & 15, quad = lane >> 4;
    extern __shared__ float sm[];
    float* __restrict__ Vs = sm;              // 512*33
    float* __restrict__ Ws = sm + 16896;      // 512*33
    float* __restrict__ vb = sm + 33792;      // 512
    float* __restrict__ pf = sm + 34304;      // 512
    float* __restrict__ c1 = sm + 34816;      // 32
    float* __restrict__ c2 = sm + 34848;      // 32
    float* __restrict__ red = sm + 34880;     // 16
    float* __restrict__ sca = sm + 34896;     // 4

    for (int i = tid; i < 34304; i += 1024) sm[i] = 0.f;  // Vs, Ws, vb
    __syncthreads();

    // initial pivot-row prefetch (row ps)
    float rk = (tid < D) ? Ts[(size_t)ps * D + tid] : 0.f;

    for (int j = 0; j < jmax; j++) {
        const int k = ps + j, sup = k + 1;
        // ---- S1: corrected pivot row -> vb (from registers), xn2 partials ----
        float val = 0.f;
        if (tid < D && tid > k) {
            float corr = 0.f;
#pragma unroll 4
            for (int t = 0; t < j; t++)
                corr += Vs[tid * 33 + t] * Ws[k * 33 + t]
                      + Ws[tid * 33 + t] * Vs[k * 33 + t];
            val = rk - corr;
            vb[tid] = val;
            if (tid == sup) sca[3] = val;  // a0
        } else if (tid == k) {
            float dc = 0.f;
            for (int t = 0; t < j; t++) dc += Vs[k * 33 + t] * Ws[k * 33 + t];
            dvec[s * D + k] = rk - 2.f * dc;
            vb[k] = 0.f;
        }
        float xp = (tid < D && tid > sup) ? val * val : 0.f;
        xp = waveSum(xp);
        if (lane == 0) red[wid] = xp;
        __syncthreads();                                   // B1

        // ---- S2': all threads: xn2, beta, v0; 32-groups: c1/c2 ----
        float xn2 = 0.f;
#pragma unroll
        for (int q = 0; q < TW; q++) xn2 += red[q];
        const float a0 = sca[3];
        const int skip = (xn2 <= 0.f);
        float beta = 0.f, v0 = 0.f, alpha = a0;
        if (!skip) {
            const float an = sqrtf(a0 * a0 + xn2);
            alpha = (a0 >= 0.f) ? -an : an;
            v0 = a0 - alpha;
            beta = 2.f / (v0 * v0 + xn2);
        }
        if (tid == sup) {
            evec[s * D + k] = skip ? a0 : alpha;
            if (!skip) vb[sup] = v0;
        }
        if (!skip) {
            const int t = tid >> 5, r = tid & 31;
            float a1 = 0.f, a2 = 0.f;
            for (int i = sup + 1 + r; i < D; i += 32) {
                const float v = vb[i];
                a1 += Ws[i * 33 + t] * v;
                a2 += Vs[i * 33 + t] * v;
            }
#pragma unroll
            for (int m = 16; m > 0; m >>= 1) {
                a1 += __shfl_xor(a1, m, 64);
                a2 += __shfl_xor(a2, m, 64);
            }
            if (r == 0) {
                c1[t] = a1 + Ws[sup * 33 + t] * v0;
                c2[t] = a2 + Vs[sup * 33 + t] * v0;
            }
        }
        __syncthreads();                                   // B2
        if (skip) {
            if (tid < D && tid >= sup) { Vg[j * D + tid] = 0.f; Wg[j * D + tid] = 0.f; }
            if (tid < D && k + 1 < D) rk = Ts[(size_t)(k + 1) * D + tid];
            __syncthreads();
            continue;
        }

        // ---- S3': symv, quarter-wave per row (4 rows/wave concurrent) ----
        const int w0 = sup & ~63;
        float pvw = 0.f;
        for (int i = sup + (wid * 4 + quad); i < D; i += 64) {
            const float* __restrict__ row = Ts + (size_t)i * D;
            float4 a4 = {0.f, 0.f, 0.f, 0.f};
            for (int c = w0 + 4 * l4; c < D; c += 64) {
                const float4 a = *(const float4*)&row[c];
                const float4 b = *(const float4*)&vb[c];
                a4.x += a.x * b.x; a4.y += a.y * b.y;
                a4.z += a.z * b.z; a4.w += a.w * b.w;
            }
            float t1 = (a4.x + a4.y) + (a4.z + a4.w);
            t1 -= Vs[i * 33 + l4] * c1[l4] + Vs[i * 33 + l4 + 16] * c1[l4 + 16]
                + Ws[i * 33 + l4] * c2[l4] + Ws[i * 33 + l4 + 16] * c2[l4 + 16];
#pragma unroll
            for (int m = 1; m < 16; m <<= 1) t1 += __shfl_xor(t1, m, 64);
            const float p = beta * t1;
            if (l4 == 0) pf[i] = p;
            pvw += p * vb[i];
        }
        pvw += __shfl_xor(pvw, 16, 64);
        pvw += __shfl_xor(pvw, 32, 64);
        if (lane == 0) red[wid] = pvw;
        __syncthreads();                                   // B3

        // ---- S5: all threads compute c; w = p - c*v; store V/W; prefetch ----
        float pv = 0.f;
#pragma unroll
        for (int q = 0; q < TW; q++) pv += red[q];
        const float cc = 0.5f * beta * pv;
        if (tid < D) {
            if (tid >= sup) {
                const float v = vb[tid];
                const float w = pf[tid] - cc * v;
                Vs[tid * 33 + j] = v;
                Ws[tid * 33 + j] = w;
                Vg[j * D + tid] = v;
                Wg[j * D + tid] = w;
            }
            if (k + 1 < D) rk = Ts[(size_t)(k + 1) * D + tid];
        }
        __syncthreads();                                   // B4
    }
    // ---- last panel: finalize trailing 2x2 ----
    if (ps + jmax == D - 2 && tid == 0) {
        const int k1 = D - 2, k2 = D - 1;
        float dc = 0.f, ec = 0.f, dc2 = 0.f;
        for (int t = 0; t < jmax; t++) {
            dc  += Vs[k1 * 33 + t] * Ws[k1 * 33 + t];
            ec  += Vs[k1 * 33 + t] * Ws[k2 * 33 + t]
                 + Ws[k1 * 33 + t] * Vs[k2 * 33 + t];
            dc2 += Vs[k2 * 33 + t] * Ws[k2 * 33 + t];
        }
        dvec[s * D + k1] = Ts[(size_t)k1 * D + k1] - 2.f * dc;
        evec[s * D + k1] = Ts[(size_t)k1 * D + k2] - ec;
        dvec[s * D + k2] = Ts[(size_t)k2 * D + k2] - 2.f * dc2;
        evec[s * D + k2] = 0.f;
    }
}

// ---------------- Kernel 2b: rank-64 symmetric update A -= V W^T + W V^T --------
__global__ __launch_bounds__(256) void latrd_update(float* __restrict__ T,
                                                    const float* __restrict__ Vt,
                                                    const float* __restrict__ Wt,
                                                    int r0) {
    const int s = blockIdx.z;
    const int i0 = r0 + 64 * blockIdx.y;
    const int j0 = r0 + 64 * blockIdx.x;
    float* __restrict__ Ts = T + (size_t)s * D * D;
    const float* __restrict__ Vg = Vt + (size_t)s * 32 * D;
    const float* __restrict__ Wg = Wt + (size_t)s * 32 * D;
    __shared__ __align__(16) float Vi[32 * 68], Wi[32 * 68], Vj[32 * 68], Wj[32 * 68];
    const int tid = threadIdx.x, tx = tid & 15, ty = tid >> 4;
    const float4 z4 = {0.f, 0.f, 0.f, 0.f};
    for (int e = tid; e < 512; e += 256) {
        const int t = e >> 4, c4 = (e & 15) * 4;
        const int gi = i0 + c4, gj = j0 + c4;
        *(float4*)&Vi[t * 68 + c4] = (gi < D) ? *(const float4*)&Vg[t * D + gi] : z4;
        *(float4*)&Wi[t * 68 + c4] = (gi < D) ? *(const float4*)&Wg[t * D + gi] : z4;
        *(float4*)&Vj[t * 68 + c4] = (gj < D) ? *(const float4*)&Vg[t * D + gj] : z4;
        *(float4*)&Wj[t * 68 + c4] = (gj < D) ? *(const float4*)&Wg[t * D + gj] : z4;
    }
    __syncthreads();
    float acc[4][4] = {{0.f}};
#pragma unroll 4
    for (int t = 0; t < 32; t++) {
        const float4 va = *(const float4*)&Vi[t * 68 + 4 * ty];
        const float4 wa = *(const float4*)&Wi[t * 68 + 4 * ty];
        const float4 vc = *(const float4*)&Vj[t * 68 + 4 * tx];
        const float4 wc = *(const float4*)&Wj[t * 68 + 4 * tx];
        const float av[4] = {va.x, va.y, va.z, va.w};
        const float aw[4] = {wa.x, wa.y, wa.z, wa.w};
        const float bv[4] = {vc.x, vc.y, vc.z, vc.w};
        const float bw[4] = {wc.x, wc.y, wc.z, wc.w};
#pragma unroll
        for (int r = 0; r < 4; r++)
#pragma unroll
            for (int q = 0; q < 4; q++) acc[r][q] += av[r] * bw[q] + aw[r] * bv[q];
    }
    const int gj = j0 + 4 * tx;
    if (gj >= D) return;
#pragma unroll
    for (int r = 0; r < 4; r++) {
        const int gi = i0 + 4 * ty + r;
        if (gi >= D) continue;
        float4 c = *(float4*)&Ts[(size_t)gi * D + gj];
        c.x -= acc[r][0]; c.y -= acc[r][1]; c.z -= acc[r][2]; c.w -= acc[r][3];
        *(float4*)&Ts[(size_t)gi * D + gj] = c;
    }
}

// ---------------- Kernel 3: bisection eigenvalues (ascending). grid 64, 512 thr --
__global__ __launch_bounds__(512) void bisect_kernel(const float* __restrict__ dvec,
                                                     const float* __restrict__ evec,
                                                     float* __restrict__ lam) {
    const int s = blockIdx.x, tid = threadIdx.x;
    const int lane = tid & 63, wid = tid >> 6;
    __shared__ float d[D], e2[D], ea[D];
    __shared__ float red[8];
    __shared__ float sh_lo, sh_hi;
    {
        const float dv = dvec[s * D + tid];
        const float ev = evec[s * D + tid];
        d[tid] = dv; ea[tid] = fabsf(ev); e2[tid] = ev * ev;
    }
    __syncthreads();
    const float rad = ea[tid] + ((tid > 0) ? ea[tid - 1] : 0.f);
    float lo = waveMin(d[tid] - rad);
    float hi = waveMax(d[tid] + rad);
    if (lane == 0) red[wid] = lo;
    __syncthreads();
    if (tid == 0) {
        float t = red[0];
        for (int q = 1; q < 8; q++) t = fminf(t, red[q]);
        sh_lo = t - 1e-3f * fmaxf(fabsf(t), 1.f);
    }
    __syncthreads();
    if (lane == 0) red[wid] = hi;
    __syncthreads();
    if (tid == 0) {
        float t = red[0];
        for (int q = 1; q < 8; q++) t = fmaxf(t, red[q]);
        sh_hi = t + 1e-3f * fmaxf(fabsf(t), 1.f);
    }
    __syncthreads();
    float a = sh_lo, b = sh_hi;
    const int j1 = tid + 1;
    for (int it = 0; it < 36; it++) {
        const float mid = 0.5f * (a + b);
        int cnt = 0;
        float q = d[0] - mid;
        cnt += (q < 0.f);
        for (int i = 1; i < D; i++) {
            float den = q;
            const float ad = fabsf(den);
            den = (ad < 1e-26f) ? ((den < 0.f) ? -1e-26f : 1e-26f) : den;
            q = d[i] - mid - e2[i - 1] / den;
            cnt += (q < 0.f);
        }
        if (cnt >= j1) b = mid; else a = mid;
    }
    lam[s * D + tid] = 0.5f * (a + b);
}

// ---------------- Kernel 4a: Cholesky panel (upper storage, L^T rows) -----------
__global__ __launch_bounds__(256) void chol_panel(float* __restrict__ M,
                                                  const float* __restrict__ lam,
                                                  float* __restrict__ logdet,
                                                  float* __restrict__ Lp,
                                                  int j0, int first) {
    const int s = blockIdx.x;
    float* __restrict__ Ms = M + (size_t)s * D * D;
    float* __restrict__ Lps = Lp + (size_t)s * 32 * D;
    const int tid = threadIdx.x, lane = tid & 63, wid = tid >> 6;
    extern __shared__ float smc[];
    float* __restrict__ P = smc;          // 32*520
    const int Wd = D - j0;
    for (int e = tid; e < 32 * D; e += 256) {
        const int t = e >> 9, i = e & 511;
        if (i >= j0) {
            const int il = i - j0;
            float v = Ms[(size_t)(j0 + t) * D + i];
            if (il == t) v += 0.01f * lam[s * D + j0 + t];
            P[t * 520 + il] = v;
        }
    }
    __syncthreads();
    float lacc = 0.f;
    for (int jl = 0; jl < 32; jl++) {
        const float pd = P[jl * 520 + jl];
        const float inv = 1.f / sqrtf(pd);
        if (tid == 0) { lacc += 0.5f * logf(pd); P[jl * 520 + jl] = sqrtf(pd); }
        for (int il = jl + 1 + tid; il < Wd; il += 256) P[jl * 520 + il] *= inv;
        __syncthreads();
        for (int kk = jl + 1 + wid; kk < 32; kk += 4) {
            const float f = P[jl * 520 + kk];
            for (int il = kk + lane; il < Wd; il += 64) P[kk * 520 + il] -= f * P[jl * 520 + il];
        }
        __syncthreads();
    }
    if (tid == 0) logdet[s] = (first ? 0.f : logdet[s]) + 2.f * lacc;
    for (int e = tid; e < 32 * D; e += 256) {
        const int t = e >> 9, i = e & 511;
        const int il = i - j0;
        if (il >= t) Ms[(size_t)(j0 + t) * D + i] = P[t * 520 + il];
        if (i >= j0 + 32) Lps[(size_t)t * D + i] = P[t * 520 + il];
    }
}

// ---------------- Kernel 4b: chol trailing update (rank 32) ---------------------
__global__ __launch_bounds__(256) void chol_update(float* __restrict__ M,
                                                   const float* __restrict__ Lp,
                                                   int r0) {
    if (blockIdx.x < blockIdx.y) return;
    const int s = blockIdx.z;
    const int i0 = r0 + 64 * blockIdx.y;
    const int j0 = r0 + 64 * blockIdx.x;
    float* __restrict__ Ms = M + (size_t)s * D * D;
    const float* __restrict__ Lps = Lp + (size_t)s * 32 * D;
    __shared__ __align__(16) float Li[32 * 68], Lj[32 * 68];
    const int tid = threadIdx.x, tx = tid & 15, ty = tid >> 4;
    const float4 z4 = {0.f, 0.f, 0.f, 0.f};
    for (int e = tid; e < 512; e += 256) {
        const int t = e >> 4, c4 = (e & 15) * 4;
        const int gi = i0 + c4, gj = j0 + c4;
        *(float4*)&Li[t * 68 + c4] = (gi < D) ? *(const float4*)&Lps[(size_t)t * D + gi] : z4;
        *(float4*)&Lj[t * 68 + c4] = (gj < D) ? *(const float4*)&Lps[(size_t)t * D + gj] : z4;
    }
    __syncthreads();
    float acc[4][4] = {{0.f}};
#pragma unroll 4
    for (int t = 0; t < 32; t++) {
        const float4 a = *(const float4*)&Li[t * 68 + 4 * ty];
        const float4 b = *(const float4*)&Lj[t * 68 + 4 * tx];
        const float av[4] = {a.x, a.y, a.z, a.w};
        const float bv[4] = {b.x, b.y, b.z, b.w};
#pragma unroll
        for (int r = 0; r < 4; r++)
#pragma unroll
            for (int q = 0; q < 4; q++) acc[r][q] += av[r] * bv[q];
    }
    const int gj = j0 + 4 * tx;
    if (gj >= D) return;
#pragma unroll
    for (int r = 0; r < 4; r++) {
        const int gi = i0 + 4 * ty + r;
        if (gi >= D) continue;
        float4 c = *(float4*)&Ms[(size_t)gi * D + gj];
        c.x -= acc[r][0]; c.y -= acc[r][1]; c.z -= acc[r][2]; c.w -= acc[r][3];
        *(float4*)&Ms[(size_t)gi * D + gj] = c;
    }
}

// ---------------- Kernel 5: invert 64x64 diagonal blocks of L (L stored ^T) -----
__global__ __launch_bounds__(64) void invdiag_kernel(const float* __restrict__ M,
                                                     float* __restrict__ invDT) {
    const int b = blockIdx.x, s = b >> 3, I = b & 7;
    const int c = threadIdx.x;
    __shared__ float Lsh[64 * 65];
    __shared__ float xsh[64 * 65];
    const float* __restrict__ Ms = M + (size_t)s * D * D;
    for (int e = c; e < 4096; e += 64) {
        const int i = e & 63, k = e >> 6;
        Lsh[i * 65 + k] = Ms[(size_t)(I * 64 + k) * D + I * 64 + i];
    }
    for (int i = 0; i < 64; i++) xsh[c * 65 + i] = (i == c) ? 1.f : 0.f;
    __syncthreads();
    for (int i = 0; i < 64; i++) {
        float t = xsh[c * 65 + i];
        for (int k = 0; k < i; k++) t -= Lsh[i * 65 + k] * xsh[c * 65 + k];
        xsh[c * 65 + i] = t / Lsh[i * 65 + i];
    }
    float* __restrict__ outp = invDT + (size_t)b * 4096 + c * 64;
    for (int i = 0; i < 64; i++) outp[i] = xsh[c * 65 + i];
}

// ---------------- Kernel 6: trsm v2 — 32-RHS panels, 2 WG/CU --------------------
// grid (64 n-panels, 64 s), 256 thr, dyn LDS = (512*33 + 2176)*4 = 76288 B
__global__ __launch_bounds__(256) void trsm_kernel(const float* __restrict__ M,
                                                   const float* __restrict__ invDT,
                                                   const float* __restrict__ xT,
                                                   const float* __restrict__ mu,
                                                   const float* __restrict__ logdet,
                                                   float* __restrict__ out) {
    extern __shared__ float smem[];
    float* __restrict__ Z = smem;            // 512 rows x stride 33
    float* __restrict__ U = smem + 512 * 33; // 2176 floats (stage 32x68 / Bs 64x34)
    const int s = blockIdx.y;
    const int n0 = blockIdx.x * 32;
    const int tid = threadIdx.x;
    const int tx = tid & 15, ty = tid >> 4;
    const float* __restrict__ Ms = M + (size_t)s * D * D;
    const float* __restrict__ mus = mu + s * D;

    for (int I = 0; I < 8; I++) {
        float acc[4][2];
#pragma unroll
        for (int r = 0; r < 4; r++) {
            const int irow = I * 64 + 4 * ty + r;
            const float m0 = mus[irow];
            const float2 xv = *(const float2*)&xT[(size_t)irow * 2048 + n0 + 2 * tx];
            acc[r][0] = xv.x - m0;
            acc[r][1] = xv.y - m0;
        }
        for (int J = 0; J < I; J++) {
#pragma unroll
            for (int h = 0; h < 2; h++) {
                __syncthreads();
                // stage U[k][i] = L[I64+i][J64+32h+k] = Ms[(J64+32h+k)*D + I64+i]
                for (int e = tid; e < 512; e += 256) {
                    const int i4 = (e & 15) * 4, kk = e >> 4;
                    *(float4*)&U[kk * 68 + i4] =
                        *(const float4*)&Ms[(size_t)(J * 64 + 32 * h + kk) * D + I * 64 + i4];
                }
                __syncthreads();
#pragma unroll 8
                for (int kk = 0; kk < 32; kk++) {
                    const float4 a = *(const float4*)&U[kk * 68 + 4 * ty];
                    const float2 b = *(const float2*)&Z[(J * 64 + 32 * h + kk) * 33 + 2 * tx];
                    const float av[4] = {a.x, a.y, a.z, a.w};
#pragma unroll
                    for (int r = 0; r < 4; r++) {
                        acc[r][0] -= av[r] * b.x;
                        acc[r][1] -= av[r] * b.y;
                    }
                }
            }
        }
        __syncthreads();
#pragma unroll
        for (int r = 0; r < 4; r++) {
            float2 v2; v2.x = acc[r][0]; v2.y = acc[r][1];
            *(float2*)&U[(4 * ty + r) * 34 + 2 * tx] = v2;
        }
        __syncthreads();
        {
            float z[4][2] = {{0.f}};
            const float* __restrict__ iD = invDT + (size_t)(s * 8 + I) * 4096;
#pragma unroll 8
            for (int kk = 0; kk < 64; kk++) {
                const float4 a = *(const float4*)&iD[kk * 64 + 4 * ty];
                const float2 b = *(const float2*)&U[kk * 34 + 2 * tx];
                const float av[4] = {a.x, a.y, a.z, a.w};
#pragma unroll
                for (int r = 0; r < 4; r++) {
                    z[r][0] += av[r] * b.x;
                    z[r][1] += av[r] * b.y;
                }
            }
#pragma unroll
            for (int r = 0; r < 4; r++) {
                float2 v2; v2.x = z[r][0]; v2.y = z[r][1];
                *(float2*)&Z[(I * 64 + 4 * ty + r) * 33 + 2 * tx] = v2;
            }
        }
    }
    __syncthreads();
    {
        const int c = tid & 31, part = tid >> 5;  // 8 parts x 64 rows
        float sum = 0.f;
        for (int i = part * 64; i < part * 64 + 64; i++) {
            const float z = Z[i * 33 + c];
            sum += z * z;
        }
        U[part * 32 + c] = sum;
    }
    __syncthreads();
    if (tid < 32) {
        float mah = 0.f;
#pragma unroll
        for (int p = 0; p < 8; p++) mah += U[p * 32 + tid];
        out[(size_t)(n0 + tid) * 64 + s] = -0.5f * (mah + logdet[s] + 940.993058f);
    }
}

extern "C" void kernel_launch(void* const* d_in, const int* in_sizes, int n_in,
                              void* d_out, int out_size, void* d_ws, size_t ws_size,
                              hipStream_t stream) {
    const float* x  = (const float*)d_in[0];   // (2048, 512)
    const float* mu = (const float*)d_in[1];   // (64, 1, 512)
    const float* sp = (const float*)d_in[3];   // (64, 1, 512, 512)
    float* out = (float*)d_out;                // (2048, 64) fp32

    float* wsf  = (float*)d_ws;
    float* MT   = wsf;                          // 16,777,216 floats
    float* dvec = wsf + (size_t)16777216;       // 32768
    float* evec = dvec + 32768;
    float* lamv = evec + 32768;
    float* logd = lamv + 32768;                 // 64
    float* Vt   = logd + 64;                    // 1,048,576
    float* Wt   = Vt + (size_t)1048576;         // 1,048,576
    float* xT   = Wt + (size_t)1048576;         // 1,048,576
    float* Lp   = Vt;                           // reuse (chol after tridiag)
    float* invDT = Vt;                          // reuse (invdiag after chol)

    // 0) transpose x; 1) m = A^T A
    xpose_kernel<<<dim3(32, 8), dim3(256), 0, stream>>>(x, xT);
    syrk_kernel<<<dim3(64, 64), dim3(256), 0, stream>>>(sp, MT);

    // 2) blocked LATRD tridiagonalization
    const size_t plds = (size_t)34900 * sizeof(float);
    for (int p = 0; p < 16; p++) {
        const int ps = 32 * p;
        const int jmax = (p == 15) ? 30 : 32;
        latrd_panel<<<dim3(64), dim3(1024), plds, stream>>>(MT, Vt, Wt, dvec, evec, ps, jmax);
        if (p < 15) {
            const int r0 = ps + 32;
            const int nt = (D - r0 + 63) / 64;
            latrd_update<<<dim3(nt, nt, 64), dim3(256), 0, stream>>>(MT, Vt, Wt, r0);
        }
    }

    // 3) all eigenvalues via Sturm bisection
    bisect_kernel<<<dim3(64), dim3(512), 0, stream>>>(dvec, evec, lamv);

    // 4) rebuild m, then blocked Cholesky of sigma
    syrk_kernel<<<dim3(64, 64), dim3(256), 0, stream>>>(sp, MT);
    const size_t clds = (size_t)(32 * 520 + 4) * sizeof(float);
    for (int p = 0; p < 16; p++) {
        const int j0 = 32 * p;
        chol_panel<<<dim3(64), dim3(256), clds, stream>>>(MT, lamv, logd, Lp, j0, p == 0 ? 1 : 0);
        if (p < 15) {
            const int r0 = j0 + 32;
            const int nt = (D - r0 + 63) / 64;
            chol_update<<<dim3(nt, nt, 64), dim3(256), 0, stream>>>(MT, Lp, r0);
        }
    }

    // 5) invert diagonal 64x64 blocks of L
    invdiag_kernel<<<dim3(512), dim3(64), 0, stream>>>(MT, invDT);

    // 6) trsm v2 + mahalanobis + epilogue
    const size_t tlds = (size_t)(512 * 33 + 2176) * sizeof(float);
    trsm_kernel<<<dim3(64, 64), dim3(256), tlds, stream>>>(MT, invDT, xT, mu, logd, out);
}

// Round 5
// 11141.620 us; speedup vs baseline: 5.8825x; 1.0772x over previous
//
#include <hip/hip_runtime.h>

#define D 512
#define TW 16

__device__ __forceinline__ float waveSum(float v) {
#pragma unroll
    for (int m = 32; m > 0; m >>= 1) v += __shfl_xor(v, m, 64);
    return v;
}
__device__ __forceinline__ float waveMin(float v) {
#pragma unroll
    for (int m = 32; m > 0; m >>= 1) v = fminf(v, __shfl_xor(v, m, 64));
    return v;
}
__device__ __forceinline__ float waveMax(float v) {
#pragma unroll
    for (int m = 32; m > 0; m >>= 1) v = fmaxf(v, __shfl_xor(v, m, 64));
    return v;
}

// ---------------- Kernel 0: xT[d][n] = x[n][d]. grid (32, 8), 256 thr ----------
__global__ __launch_bounds__(256) void xpose_kernel(const float* __restrict__ x,
                                                    float* __restrict__ xT) {
    __shared__ float t[64][65];
    const int bx = blockIdx.x * 64;  // n block
    const int by = blockIdx.y * 64;  // d block
    const int tid = threadIdx.x;
    const int lx = tid & 63, lq = tid >> 6;
#pragma unroll
    for (int r = 0; r < 64; r += 4)
        t[r + lq][lx] = x[(size_t)(bx + r + lq) * D + by + lx];
    __syncthreads();
#pragma unroll
    for (int r = 0; r < 64; r += 4)
        xT[(size_t)(by + r + lq) * 2048 + bx + lx] = t[lx][r + lq];
}

// ---------------- Kernel 1: m = A^T A (per s). grid (64 tiles, 64 s), 256 thr ----
__global__ __launch_bounds__(256) void syrk_kernel(const float* __restrict__ sp,
                                                   float* __restrict__ M) {
    const int s = blockIdx.y;
    const int I = blockIdx.x >> 3, J = blockIdx.x & 7;
    const int tx = threadIdx.x & 15, ty = threadIdx.x >> 4;
    const float* __restrict__ A = sp + (size_t)s * D * D;
    __shared__ __align__(16) float As[64 * 68];
    __shared__ __align__(16) float Bs[64 * 68];
    float acc[4][4];
#pragma unroll
    for (int r = 0; r < 4; r++)
#pragma unroll
        for (int q = 0; q < 4; q++) acc[r][q] = 0.f;

    for (int k0 = 0; k0 < D; k0 += 64) {
        for (int e = threadIdx.x; e < 4096; e += 256) {
            const int col = e & 63, kr = e >> 6;
            As[kr * 68 + col] = A[(size_t)(k0 + kr) * D + I * 64 + col];
            Bs[kr * 68 + col] = A[(size_t)(k0 + kr) * D + J * 64 + col];
        }
        __syncthreads();
#pragma unroll 4
        for (int k = 0; k < 64; k++) {
            const float4 a = *(const float4*)&As[k * 68 + 4 * ty];
            const float4 b = *(const float4*)&Bs[k * 68 + 4 * tx];
            const float av[4] = {a.x, a.y, a.z, a.w};
            const float bv[4] = {b.x, b.y, b.z, b.w};
#pragma unroll
            for (int r = 0; r < 4; r++)
#pragma unroll
                for (int q = 0; q < 4; q++) acc[r][q] += av[r] * bv[q];
        }
        __syncthreads();
    }
#pragma unroll
    for (int r = 0; r < 4; r++) {
        float4 v4;
        v4.x = acc[r][0]; v4.y = acc[r][1]; v4.z = acc[r][2]; v4.w = acc[r][3];
        const size_t off = (size_t)s * D * D + (size_t)(I * 64 + 4 * ty + r) * D + J * 64 + 4 * tx;
        *(float4*)(M + off) = v4;
    }
}

// ---------------- Kernel 2a: LATRD panel v2. 64 WGs x 1024 thr ------------------
__global__ __launch_bounds__(1024) void latrd_panel(float* __restrict__ T,
                                                    float* __restrict__ Vt,
                                                    float* __restrict__ Wt,
                                                    float* __restrict__ dvec,
                                                    float* __restrict__ evec,
                                                    int ps, int jmax) {
    const int s = blockIdx.x;
    float* __restrict__ Ts = T + (size_t)s * D * D;
    float* __restrict__ Vg = Vt + (size_t)s * 32 * D;
    float* __restrict__ Wg = Wt + (size_t)s * 32 * D;
    const int tid = threadIdx.x, lane = tid & 63, wid = tid >> 6;
    const int l4 = lane & 15, quad = lane >> 4;
    extern __shared__ float sm[];
    float* __restrict__ Vs = sm;              // 512*33
    float* __restrict__ Ws = sm + 16896;      // 512*33
    float* __restrict__ vb = sm + 33792;      // 512
    float* __restrict__ pf = sm + 34304;      // 512
    float* __restrict__ c1 = sm + 34816;      // 32
    float* __restrict__ c2 = sm + 34848;      // 32
    float* __restrict__ red = sm + 34880;     // 16
    float* __restrict__ sca = sm + 34896;     // 4

    for (int i = tid; i < 34304; i += 1024) sm[i] = 0.f;  // Vs, Ws, vb
    __syncthreads();

    float rk = (tid < D) ? Ts[(size_t)ps * D + tid] : 0.f;

    for (int j = 0; j < jmax; j++) {
        const int k = ps + j, sup = k + 1;
        // ---- S1: corrected pivot row -> vb, xn2 partials ----
        float val = 0.f;
        if (tid < D && tid > k) {
            float corr = 0.f;
#pragma unroll 4
            for (int t = 0; t < j; t++)
                corr += Vs[tid * 33 + t] * Ws[k * 33 + t]
                      + Ws[tid * 33 + t] * Vs[k * 33 + t];
            val = rk - corr;
            vb[tid] = val;
            if (tid == sup) sca[3] = val;  // a0
        } else if (tid == k) {
            float dc = 0.f;
            for (int t = 0; t < j; t++) dc += Vs[k * 33 + t] * Ws[k * 33 + t];
            dvec[s * D + k] = rk - 2.f * dc;
            vb[k] = 0.f;
        }
        float xp = (tid < D && tid > sup) ? val * val : 0.f;
        xp = waveSum(xp);
        if (lane == 0) red[wid] = xp;
        __syncthreads();                                   // B1

        // ---- S2': all threads: xn2, beta, v0; 32-groups: c1/c2 ----
        float xn2 = 0.f;
#pragma unroll
        for (int q = 0; q < TW; q++) xn2 += red[q];
        const float a0 = sca[3];
        const int skip = (xn2 <= 0.f);
        float beta = 0.f, v0 = 0.f, alpha = a0;
        if (!skip) {
            const float an = sqrtf(a0 * a0 + xn2);
            alpha = (a0 >= 0.f) ? -an : an;
            v0 = a0 - alpha;
            beta = 2.f / (v0 * v0 + xn2);
        }
        if (tid == sup) {
            evec[s * D + k] = skip ? a0 : alpha;
            if (!skip) vb[sup] = v0;
        }
        if (!skip) {
            const int t = tid >> 5, r = tid & 31;
            float a1 = 0.f, a2 = 0.f;
            for (int i = sup + 1 + r; i < D; i += 32) {
                const float v = vb[i];
                a1 += Ws[i * 33 + t] * v;
                a2 += Vs[i * 33 + t] * v;
            }
#pragma unroll
            for (int m = 16; m > 0; m >>= 1) {
                a1 += __shfl_xor(a1, m, 64);
                a2 += __shfl_xor(a2, m, 64);
            }
            if (r == 0) {
                c1[t] = a1 + Ws[sup * 33 + t] * v0;
                c2[t] = a2 + Vs[sup * 33 + t] * v0;
            }
        }
        __syncthreads();                                   // B2
        if (skip) {
            if (tid < D && tid >= sup) { Vg[j * D + tid] = 0.f; Wg[j * D + tid] = 0.f; }
            if (tid < D && k + 1 < D) rk = Ts[(size_t)(k + 1) * D + tid];
            __syncthreads();
            continue;
        }

        // ---- S3': symv, quarter-wave per row ----
        const int w0 = sup & ~63;
        float pvw = 0.f;
        for (int i = sup + (wid * 4 + quad); i < D; i += 64) {
            const float* __restrict__ row = Ts + (size_t)i * D;
            float4 a4 = {0.f, 0.f, 0.f, 0.f};
            for (int c = w0 + 4 * l4; c < D; c += 64) {
                const float4 a = *(const float4*)&row[c];
                const float4 b = *(const float4*)&vb[c];
                a4.x += a.x * b.x; a4.y += a.y * b.y;
                a4.z += a.z * b.z; a4.w += a.w * b.w;
            }
            float t1 = (a4.x + a4.y) + (a4.z + a4.w);
            t1 -= Vs[i * 33 + l4] * c1[l4] + Vs[i * 33 + l4 + 16] * c1[l4 + 16]
                + Ws[i * 33 + l4] * c2[l4] + Ws[i * 33 + l4 + 16] * c2[l4 + 16];
#pragma unroll
            for (int m = 1; m < 16; m <<= 1) t1 += __shfl_xor(t1, m, 64);
            const float p = beta * t1;
            if (l4 == 0) pf[i] = p;
            pvw += p * vb[i];
        }
        pvw += __shfl_xor(pvw, 16, 64);
        pvw += __shfl_xor(pvw, 32, 64);
        if (lane == 0) red[wid] = pvw;
        __syncthreads();                                   // B3

        // ---- S5 ----
        float pv = 0.f;
#pragma unroll
        for (int q = 0; q < TW; q++) pv += red[q];
        const float cc = 0.5f * beta * pv;
        if (tid < D) {
            if (tid >= sup) {
                const float v = vb[tid];
                const float w = pf[tid] - cc * v;
                Vs[tid * 33 + j] = v;
                Ws[tid * 33 + j] = w;
                Vg[j * D + tid] = v;
                Wg[j * D + tid] = w;
            }
            if (k + 1 < D) rk = Ts[(size_t)(k + 1) * D + tid];
        }
        __syncthreads();                                   // B4
    }
    if (ps + jmax == D - 2 && tid == 0) {
        const int k1 = D - 2, k2 = D - 1;
        float dc = 0.f, ec = 0.f, dc2 = 0.f;
        for (int t = 0; t < jmax; t++) {
            dc  += Vs[k1 * 33 + t] * Ws[k1 * 33 + t];
            ec  += Vs[k1 * 33 + t] * Ws[k2 * 33 + t]
                 + Ws[k1 * 33 + t] * Vs[k2 * 33 + t];
            dc2 += Vs[k2 * 33 + t] * Ws[k2 * 33 + t];
        }
        dvec[s * D + k1] = Ts[(size_t)k1 * D + k1] - 2.f * dc;
        evec[s * D + k1] = Ts[(size_t)k1 * D + k2] - ec;
        dvec[s * D + k2] = Ts[(size_t)k2 * D + k2] - 2.f * dc2;
        evec[s * D + k2] = 0.f;
    }
}

// ---------------- Kernel 2b: rank-64 symmetric update A -= V W^T + W V^T --------
__global__ __launch_bounds__(256) void latrd_update(float* __restrict__ T,
                                                    const float* __restrict__ Vt,
                                                    const float* __restrict__ Wt,
                                                    int r0) {
    const int s = blockIdx.z;
    const int i0 = r0 + 64 * blockIdx.y;
    const int j0 = r0 + 64 * blockIdx.x;
    float* __restrict__ Ts = T + (size_t)s * D * D;
    const float* __restrict__ Vg = Vt + (size_t)s * 32 * D;
    const float* __restrict__ Wg = Wt + (size_t)s * 32 * D;
    __shared__ __align__(16) float Vi[32 * 68], Wi[32 * 68], Vj[32 * 68], Wj[32 * 68];
    const int tid = threadIdx.x, tx = tid & 15, ty = tid >> 4;
    const float4 z4 = {0.f, 0.f, 0.f, 0.f};
    for (int e = tid; e < 512; e += 256) {
        const int t = e >> 4, c4 = (e & 15) * 4;
        const int gi = i0 + c4, gj = j0 + c4;
        *(float4*)&Vi[t * 68 + c4] = (gi < D) ? *(const float4*)&Vg[t * D + gi] : z4;
        *(float4*)&Wi[t * 68 + c4] = (gi < D) ? *(const float4*)&Wg[t * D + gi] : z4;
        *(float4*)&Vj[t * 68 + c4] = (gj < D) ? *(const float4*)&Vg[t * D + gj] : z4;
        *(float4*)&Wj[t * 68 + c4] = (gj < D) ? *(const float4*)&Wg[t * D + gj] : z4;
    }
    __syncthreads();
    float acc[4][4] = {{0.f}};
#pragma unroll 4
    for (int t = 0; t < 32; t++) {
        const float4 va = *(const float4*)&Vi[t * 68 + 4 * ty];
        const float4 wa = *(const float4*)&Wi[t * 68 + 4 * ty];
        const float4 vc = *(const float4*)&Vj[t * 68 + 4 * tx];
        const float4 wc = *(const float4*)&Wj[t * 68 + 4 * tx];
        const float av[4] = {va.x, va.y, va.z, va.w};
        const float aw[4] = {wa.x, wa.y, wa.z, wa.w};
        const float bv[4] = {vc.x, vc.y, vc.z, vc.w};
        const float bw[4] = {wc.x, wc.y, wc.z, wc.w};
#pragma unroll
        for (int r = 0; r < 4; r++)
#pragma unroll
            for (int q = 0; q < 4; q++) acc[r][q] += av[r] * bw[q] + aw[r] * bv[q];
    }
    const int gj = j0 + 4 * tx;
    if (gj >= D) return;
#pragma unroll
    for (int r = 0; r < 4; r++) {
        const int gi = i0 + 4 * ty + r;
        if (gi >= D) continue;
        float4 c = *(float4*)&Ts[(size_t)gi * D + gj];
        c.x -= acc[r][0]; c.y -= acc[r][1]; c.z -= acc[r][2]; c.w -= acc[r][3];
        *(float4*)&Ts[(size_t)gi * D + gj] = c;
    }
}

// ---------------- Kernel 3: bisection eigenvalues (ascending). grid 64, 512 thr --
__global__ __launch_bounds__(512) void bisect_kernel(const float* __restrict__ dvec,
                                                     const float* __restrict__ evec,
                                                     float* __restrict__ lam) {
    const int s = blockIdx.x, tid = threadIdx.x;
    const int lane = tid & 63, wid = tid >> 6;
    __shared__ float d[D], e2[D], ea[D];
    __shared__ float red[8];
    __shared__ float sh_lo, sh_hi;
    {
        const float dv = dvec[s * D + tid];
        const float ev = evec[s * D + tid];
        d[tid] = dv; ea[tid] = fabsf(ev); e2[tid] = ev * ev;
    }
    __syncthreads();
    const float rad = ea[tid] + ((tid > 0) ? ea[tid - 1] : 0.f);
    float lo = waveMin(d[tid] - rad);
    float hi = waveMax(d[tid] + rad);
    if (lane == 0) red[wid] = lo;
    __syncthreads();
    if (tid == 0) {
        float t = red[0];
        for (int q = 1; q < 8; q++) t = fminf(t, red[q]);
        sh_lo = t - 1e-3f * fmaxf(fabsf(t), 1.f);
    }
    __syncthreads();
    if (lane == 0) red[wid] = hi;
    __syncthreads();
    if (tid == 0) {
        float t = red[0];
        for (int q = 1; q < 8; q++) t = fmaxf(t, red[q]);
        sh_hi = t + 1e-3f * fmaxf(fabsf(t), 1.f);
    }
    __syncthreads();
    float a = sh_lo, b = sh_hi;
    const int j1 = tid + 1;
    for (int it = 0; it < 36; it++) {
        const float mid = 0.5f * (a + b);
        int cnt = 0;
        float q = d[0] - mid;
        cnt += (q < 0.f);
        for (int i = 1; i < D; i++) {
            float den = q;
            const float ad = fabsf(den);
            den = (ad < 1e-26f) ? ((den < 0.f) ? -1e-26f : 1e-26f) : den;
            q = d[i] - mid - e2[i - 1] / den;
            cnt += (q < 0.f);
        }
        if (cnt >= j1) b = mid; else a = mid;
    }
    lam[s * D + tid] = 0.5f * (a + b);
}

// ---------------- Kernel 4a: Cholesky panel (upper storage, L^T rows) -----------
__global__ __launch_bounds__(256) void chol_panel(float* __restrict__ M,
                                                  const float* __restrict__ lam,
                                                  float* __restrict__ logdet,
                                                  float* __restrict__ Lp,
                                                  int j0, int first) {
    const int s = blockIdx.x;
    float* __restrict__ Ms = M + (size_t)s * D * D;
    float* __restrict__ Lps = Lp + (size_t)s * 32 * D;
    const int tid = threadIdx.x, lane = tid & 63, wid = tid >> 6;
    extern __shared__ float smc[];
    float* __restrict__ P = smc;          // 32*520
    const int Wd = D - j0;
    for (int e = tid; e < 32 * D; e += 256) {
        const int t = e >> 9, i = e & 511;
        if (i >= j0) {
            const int il = i - j0;
            float v = Ms[(size_t)(j0 + t) * D + i];
            if (il == t) v += 0.01f * lam[s * D + j0 + t];
            P[t * 520 + il] = v;
        }
    }
    __syncthreads();
    float lacc = 0.f;
    for (int jl = 0; jl < 32; jl++) {
        const float pd = P[jl * 520 + jl];
        const float inv = 1.f / sqrtf(pd);
        if (tid == 0) { lacc += 0.5f * logf(pd); P[jl * 520 + jl] = sqrtf(pd); }
        for (int il = jl + 1 + tid; il < Wd; il += 256) P[jl * 520 + il] *= inv;
        __syncthreads();
        for (int kk = jl + 1 + wid; kk < 32; kk += 4) {
            const float f = P[jl * 520 + kk];
            for (int il = kk + lane; il < Wd; il += 64) P[kk * 520 + il] -= f * P[jl * 520 + il];
        }
        __syncthreads();
    }
    if (tid == 0) logdet[s] = (first ? 0.f : logdet[s]) + 2.f * lacc;
    for (int e = tid; e < 32 * D; e += 256) {
        const int t = e >> 9, i = e & 511;
        const int il = i - j0;
        if (il >= t) Ms[(size_t)(j0 + t) * D + i] = P[t * 520 + il];
        if (i >= j0 + 32) Lps[(size_t)t * D + i] = P[t * 520 + il];
    }
}

// ---------------- Kernel 4b: chol trailing update (rank 32) ---------------------
__global__ __launch_bounds__(256) void chol_update(float* __restrict__ M,
                                                   const float* __restrict__ Lp,
                                                   int r0) {
    if (blockIdx.x < blockIdx.y) return;
    const int s = blockIdx.z;
    const int i0 = r0 + 64 * blockIdx.y;
    const int j0 = r0 + 64 * blockIdx.x;
    float* __restrict__ Ms = M + (size_t)s * D * D;
    const float* __restrict__ Lps = Lp + (size_t)s * 32 * D;
    __shared__ __align__(16) float Li[32 * 68], Lj[32 * 68];
    const int tid = threadIdx.x, tx = tid & 15, ty = tid >> 4;
    const float4 z4 = {0.f, 0.f, 0.f, 0.f};
    for (int e = tid; e < 512; e += 256) {
        const int t = e >> 4, c4 = (e & 15) * 4;
        const int gi = i0 + c4, gj = j0 + c4;
        *(float4*)&Li[t * 68 + c4] = (gi < D) ? *(const float4*)&Lps[(size_t)t * D + gi] : z4;
        *(float4*)&Lj[t * 68 + c4] = (gj < D) ? *(const float4*)&Lps[(size_t)t * D + gj] : z4;
    }
    __syncthreads();
    float acc[4][4] = {{0.f}};
#pragma unroll 4
    for (int t = 0; t < 32; t++) {
        const float4 a = *(const float4*)&Li[t * 68 + 4 * ty];
        const float4 b = *(const float4*)&Lj[t * 68 + 4 * tx];
        const float av[4] = {a.x, a.y, a.z, a.w};
        const float bv[4] = {b.x, b.y, b.z, b.w};
#pragma unroll
        for (int r = 0; r < 4; r++)
#pragma unroll
            for (int q = 0; q < 4; q++) acc[r][q] += av[r] * bv[q];
    }
    const int gj = j0 + 4 * tx;
    if (gj >= D) return;
#pragma unroll
    for (int r = 0; r < 4; r++) {
        const int gi = i0 + 4 * ty + r;
        if (gi >= D) continue;
        float4 c = *(float4*)&Ms[(size_t)gi * D + gj];
        c.x -= acc[r][0]; c.y -= acc[r][1]; c.z -= acc[r][2]; c.w -= acc[r][3];
        *(float4*)&Ms[(size_t)gi * D + gj] = c;
    }
}

// ---------------- Kernel 5: invert 64x64 diagonal blocks of L (L stored ^T) -----
__global__ __launch_bounds__(64) void invdiag_kernel(const float* __restrict__ M,
                                                     float* __restrict__ invDT) {
    const int b = blockIdx.x, s = b >> 3, I = b & 7;
    const int c = threadIdx.x;
    __shared__ float Lsh[64 * 65];
    __shared__ float xsh[64 * 65];
    const float* __restrict__ Ms = M + (size_t)s * D * D;
    for (int e = c; e < 4096; e += 64) {
        const int i = e & 63, k = e >> 6;
        Lsh[i * 65 + k] = Ms[(size_t)(I * 64 + k) * D + I * 64 + i];
    }
    for (int i = 0; i < 64; i++) xsh[c * 65 + i] = (i == c) ? 1.f : 0.f;
    __syncthreads();
    for (int i = 0; i < 64; i++) {
        float t = xsh[c * 65 + i];
        for (int k = 0; k < i; k++) t -= Lsh[i * 65 + k] * xsh[c * 65 + k];
        xsh[c * 65 + i] = t / Lsh[i * 65 + i];
    }
    float* __restrict__ outp = invDT + (size_t)b * 4096 + c * 64;
    for (int i = 0; i < 64; i++) outp[i] = xsh[c * 65 + i];  // invDT[b][c][i] = invL[i][c]
}

// ---------------- Kernel 5b: triangular inverse step ----------------------------
// invL[I][J] = -invD_I * sum_{K=J..I-1} L[I][K] * invL[K][J].  Stored into the
// strictly-lower blocks of MT (row-major). grid (J<I, 64 s), 256 thr.
__global__ __launch_bounds__(256) void triinv_step(float* __restrict__ M,
                                                   const float* __restrict__ invDT,
                                                   int I) {
    const int J = blockIdx.x, s = blockIdx.y;
    float* __restrict__ Ms = M + (size_t)s * D * D;
    __shared__ __align__(16) float Ls[64 * 68];
    __shared__ __align__(16) float Bs[64 * 68];
    __shared__ __align__(16) float Ss[64 * 68];
    const int tid = threadIdx.x, tx = tid & 15, ty = tid >> 4;
    float acc[4][4] = {{0.f}};
    for (int K = J; K < I; K++) {
        __syncthreads();
        for (int e = tid; e < 4096; e += 256) {
            const int k = e >> 6, r = e & 63;
            Ls[k * 68 + r] = Ms[(size_t)(K * 64 + k) * D + I * 64 + r];  // L[I][K][r][k]
        }
        if (K == J) {
            const float* __restrict__ dJ = invDT + ((size_t)s * 8 + J) * 4096;
            for (int e = tid; e < 4096; e += 256) {
                const int c = e >> 6, k = e & 63;
                Bs[k * 68 + c] = dJ[c * 64 + k];   // invL[J][J][k][c]
            }
        } else {
            for (int e = tid; e < 4096; e += 256) {
                const int k = e >> 6, c = e & 63;
                Bs[k * 68 + c] = Ms[(size_t)(K * 64 + k) * D + J * 64 + c];
            }
        }
        __syncthreads();
#pragma unroll 4
        for (int k = 0; k < 64; k++) {
            const float4 a = *(const float4*)&Ls[k * 68 + 4 * ty];
            const float4 b = *(const float4*)&Bs[k * 68 + 4 * tx];
            const float av[4] = {a.x, a.y, a.z, a.w};
            const float bv[4] = {b.x, b.y, b.z, b.w};
#pragma unroll
            for (int r = 0; r < 4; r++)
#pragma unroll
                for (int q = 0; q < 4; q++) acc[r][q] += av[r] * bv[q];
        }
    }
    __syncthreads();
#pragma unroll
    for (int r = 0; r < 4; r++) {
        float4 v4;
        v4.x = acc[r][0]; v4.y = acc[r][1]; v4.z = acc[r][2]; v4.w = acc[r][3];
        *(float4*)&Ss[(4 * ty + r) * 68 + 4 * tx] = v4;
    }
    {
        const float* __restrict__ dI = invDT + ((size_t)s * 8 + I) * 4096;
        for (int e = tid; e < 4096; e += 256) {
            const int k = e >> 6, r = e & 63;
            Ls[k * 68 + r] = dI[k * 64 + r];       // Ds[k][r] = invD_I[r][k]
        }
    }
    __syncthreads();
    float o[4][4] = {{0.f}};
#pragma unroll 4
    for (int k = 0; k < 64; k++) {
        const float4 a = *(const float4*)&Ls[k * 68 + 4 * ty];
        const float4 b = *(const float4*)&Ss[k * 68 + 4 * tx];
        const float av[4] = {a.x, a.y, a.z, a.w};
        const float bv[4] = {b.x, b.y, b.z, b.w};
#pragma unroll
        for (int r = 0; r < 4; r++)
#pragma unroll
            for (int q = 0; q < 4; q++) o[r][q] += av[r] * bv[q];
    }
#pragma unroll
    for (int r = 0; r < 4; r++) {
        float4 v4;
        v4.x = -o[r][0]; v4.y = -o[r][1]; v4.z = -o[r][2]; v4.w = -o[r][3];
        *(float4*)&Ms[(size_t)(I * 64 + 4 * ty + r) * D + J * 64 + 4 * tx] = v4;
    }
}

// ---------------- Kernel 6: fused GEMM + mahalanobis ----------------------------
// maha_n = sum_i ( sum_{k<=i} invL[i][k] * (x[k][n]-mu[k]) )^2, triangular k-bound.
// grid (32 n-blocks of 64, 64 s), 256 thr. 128-row i-chunks, 32-wide k-chunks.
__global__ __launch_bounds__(256) void gemm_maha(const float* __restrict__ M,
                                                 const float* __restrict__ invDT,
                                                 const float* __restrict__ xT,
                                                 const float* __restrict__ mu,
                                                 const float* __restrict__ logdet,
                                                 float* __restrict__ out) {
    const int s = blockIdx.y;
    const int n0 = blockIdx.x * 64;
    const int tid = threadIdx.x, tx = tid & 15, ty = tid >> 4;
    const float* __restrict__ Ms = M + (size_t)s * D * D;
    const float* __restrict__ mus = mu + s * D;
    __shared__ __align__(16) float As[32 * 136];
    __shared__ __align__(16) float Bs[32 * 68];
    __shared__ float red[16 * 68];
    float cs[4] = {0.f, 0.f, 0.f, 0.f};

    for (int ci = 0; ci < 4; ci++) {
        const int i0 = ci * 128;
        float acc[8][4];
#pragma unroll
        for (int r = 0; r < 8; r++)
#pragma unroll
            for (int q = 0; q < 4; q++) acc[r][q] = 0.f;
        const int nkc = (ci + 1) * 4;
        for (int kc = 0; kc < nkc; kc++) {
            const int k0 = kc * 32, kb = k0 >> 6;
            __syncthreads();
            // A-tile: invL rows i0..i0+128, cols k0..k0+32 (strictly-lower from MT)
            for (int e = tid; e < 4096; e += 256) {
                const int il = e >> 5, kk = e & 31;
                const int ib = (i0 + il) >> 6;
                As[kk * 136 + il] = (kb < ib) ? Ms[(size_t)(i0 + il) * D + k0 + kk] : 0.f;
            }
            if (kb >= 2 * ci) {  // diagonal 64-block slice from invDT
                const float* __restrict__ dB = invDT + ((size_t)s * 8 + kb) * 4096
                                             + (size_t)(k0 & 63) * 64;
                const int ilb = (kb - 2 * ci) * 64;
                for (int e = tid; e < 2048; e += 256) {
                    const int ii = e & 63, kk = e >> 6;
                    As[kk * 136 + ilb + ii] = dB[kk * 64 + ii];
                }
            }
            // B-tile: diff[k][n]
            for (int e = tid; e < 2048; e += 256) {
                const int nn = e & 63, kk = e >> 6;
                Bs[kk * 68 + nn] = xT[(size_t)(k0 + kk) * 2048 + n0 + nn] - mus[k0 + kk];
            }
            __syncthreads();
#pragma unroll 8
            for (int kk = 0; kk < 32; kk++) {
                const float4 a0 = *(const float4*)&As[kk * 136 + 8 * ty];
                const float4 a1 = *(const float4*)&As[kk * 136 + 8 * ty + 4];
                const float4 b  = *(const float4*)&Bs[kk * 68 + 4 * tx];
                const float av[8] = {a0.x, a0.y, a0.z, a0.w, a1.x, a1.y, a1.z, a1.w};
                const float bv[4] = {b.x, b.y, b.z, b.w};
#pragma unroll
                for (int r = 0; r < 8; r++)
#pragma unroll
                    for (int q = 0; q < 4; q++) acc[r][q] += av[r] * bv[q];
            }
        }
#pragma unroll
        for (int r = 0; r < 8; r++)
#pragma unroll
            for (int q = 0; q < 4; q++) cs[q] += acc[r][q] * acc[r][q];
    }
    __syncthreads();
#pragma unroll
    for (int q = 0; q < 4; q++) red[ty * 68 + 4 * tx + q] = cs[q];
    __syncthreads();
    if (tid < 64) {
        float mah = 0.f;
#pragma unroll
        for (int t = 0; t < 16; t++) mah += red[t * 68 + tid];
        out[(size_t)(n0 + tid) * 64 + s] = -0.5f * (mah + logdet[s] + 940.993058f);
    }
}

extern "C" void kernel_launch(void* const* d_in, const int* in_sizes, int n_in,
                              void* d_out, int out_size, void* d_ws, size_t ws_size,
                              hipStream_t stream) {
    const float* x  = (const float*)d_in[0];   // (2048, 512)
    const float* mu = (const float*)d_in[1];   // (64, 1, 512)
    const float* sp = (const float*)d_in[3];   // (64, 1, 512, 512)
    float* out = (float*)d_out;                // (2048, 64) fp32

    float* wsf  = (float*)d_ws;
    float* MT   = wsf;                          // 16,777,216 floats
    float* dvec = wsf + (size_t)16777216;       // 32768
    float* evec = dvec + 32768;
    float* lamv = evec + 32768;
    float* logd = lamv + 32768;                 // 64
    float* Vt   = logd + 64;                    // 1,048,576
    float* Wt   = Vt + (size_t)1048576;         // 1,048,576
    float* xT   = Wt + (size_t)1048576;         // 1,048,576
    float* Lp   = Vt;                           // reuse (chol after tridiag)
    float* invDT = Vt;                          // reuse (after chol; spans Vt+Wt)

    // 0) transpose x; 1) m = A^T A
    xpose_kernel<<<dim3(32, 8), dim3(256), 0, stream>>>(x, xT);
    syrk_kernel<<<dim3(64, 64), dim3(256), 0, stream>>>(sp, MT);

    // 2) blocked LATRD tridiagonalization
    const size_t plds = (size_t)34900 * sizeof(float);
    for (int p = 0; p < 16; p++) {
        const int ps = 32 * p;
        const int jmax = (p == 15) ? 30 : 32;
        latrd_panel<<<dim3(64), dim3(1024), plds, stream>>>(MT, Vt, Wt, dvec, evec, ps, jmax);
        if (p < 15) {
            const int r0 = ps + 32;
            const int nt = (D - r0 + 63) / 64;
            latrd_update<<<dim3(nt, nt, 64), dim3(256), 0, stream>>>(MT, Vt, Wt, r0);
        }
    }

    // 3) all eigenvalues via Sturm bisection
    bisect_kernel<<<dim3(64), dim3(512), 0, stream>>>(dvec, evec, lamv);

    // 4) rebuild m, then blocked Cholesky of sigma (L stored transposed in upper)
    syrk_kernel<<<dim3(64, 64), dim3(256), 0, stream>>>(sp, MT);
    const size_t clds = (size_t)(32 * 520 + 4) * sizeof(float);
    for (int p = 0; p < 16; p++) {
        const int j0 = 32 * p;
        chol_panel<<<dim3(64), dim3(256), clds, stream>>>(MT, lamv, logd, Lp, j0, p == 0 ? 1 : 0);
        if (p < 15) {
            const int r0 = j0 + 32;
            const int nt = (D - r0 + 63) / 64;
            chol_update<<<dim3(nt, nt, 64), dim3(256), 0, stream>>>(MT, Lp, r0);
        }
    }

    // 5) full triangular inverse: diag blocks, then off-diag into MT lower
    invdiag_kernel<<<dim3(512), dim3(64), 0, stream>>>(MT, invDT);
    for (int I = 1; I < 8; I++)
        triinv_step<<<dim3(I, 64), dim3(256), 0, stream>>>(MT, invDT, I);

    // 6) fused GEMM + mahalanobis + epilogue
    gemm_maha<<<dim3(32, 64), dim3(256), 0, stream>>>(MT, invDT, xT, mu, logd, out);
}